// Round 1
// baseline (2351.742 us; speedup 1.0000x reference)
//
#include <hip/hip_runtime.h>
#include <math.h>

#define N_NODES 20000
#define N_EDGES 640000
#define D 128      // NODE_DIM == HID
#define ED 64      // EDGE_DIM
#define EPS 1e-8f
#define TE 32      // edges per block
#define TN 32      // nodes per block

__device__ __forceinline__ float silu_f(float x) {
    return x / (1.0f + __expf(-x));
}

// ---------------------------------------------------------------------------
// init: zero the aggregation buffer, seed out_coords with coords
// ---------------------------------------------------------------------------
__global__ void init_kernel(const float* __restrict__ coords,
                            float* __restrict__ aggr,
                            float* __restrict__ out_coords) {
    int stride = gridDim.x * blockDim.x;
    int i = blockIdx.x * blockDim.x + threadIdx.x;
    for (int idx = i; idx < N_NODES * D; idx += stride) aggr[idx] = 0.0f;
    for (int idx = i; idx < N_NODES * 3; idx += stride) out_coords[idx] = coords[idx];
}

// ---------------------------------------------------------------------------
// edge kernel: fused edge-MLP (2 layers) + message scatter + coord-MLP +
// coord update scatter. 32 edges per block, 256 threads.
// Thread mapping for the 128-wide layers: eg = tid>>5 (4 edges each),
// jg = tid&31 (4 outputs each) -> 4x4 register tile per thread.
// ---------------------------------------------------------------------------
__global__ __launch_bounds__(256, 2)
void edge_kernel(const float* __restrict__ node_feat,
                 const int* __restrict__ edge_index,
                 const float* __restrict__ edge_attr,
                 const float* __restrict__ coords,
                 const float* __restrict__ eW1, const float* __restrict__ eb1,
                 const float* __restrict__ eW2, const float* __restrict__ eb2,
                 const float* __restrict__ cW1, const float* __restrict__ cb1,
                 const float* __restrict__ cW2, const float* __restrict__ cb2,
                 float* __restrict__ aggr, float* __restrict__ out_coords) {
    __shared__ float feat[TE][320];   // concat(nf[src], nf[dst], edge_attr)
    __shared__ float h1s[TE][D];
    __shared__ int s_src[TE], s_dst[TE];

    const int tid = threadIdx.x;
    const int E0 = blockIdx.x * TE;

    if (tid < TE) {
        s_src[tid] = edge_index[E0 + tid];
        s_dst[tid] = edge_index[N_EDGES + E0 + tid];
    }
    __syncthreads();

    // stage edge features in LDS (coalesced along feature dim)
    for (int idx = tid; idx < TE * D; idx += 256) {
        int e = idx >> 7, j = idx & 127;
        feat[e][j]       = node_feat[s_src[e] * D + j];
        feat[e][128 + j] = node_feat[s_dst[e] * D + j];
    }
    for (int idx = tid; idx < TE * ED; idx += 256) {
        int e = idx >> 6, j = idx & 63;
        feat[e][256 + j] = edge_attr[(E0 + e) * ED + j];
    }
    __syncthreads();

    const int eg = tid >> 5;        // 0..7, edges eg*4 .. eg*4+3
    const int jg = tid & 31;        // outputs jg*4 .. jg*4+3
    const int j0 = jg * 4;

    // ---- edge MLP layer 1: [320] -> [128], SiLU ----
    float acc[4][4];
    {
        float4 b = *(const float4*)&eb1[j0];
        #pragma unroll
        for (int i = 0; i < 4; ++i) { acc[i][0]=b.x; acc[i][1]=b.y; acc[i][2]=b.z; acc[i][3]=b.w; }
    }
    for (int k = 0; k < 320; ++k) {
        float4 w = *(const float4*)&eW1[k * D + j0];
        #pragma unroll
        for (int i = 0; i < 4; ++i) {
            float f = feat[eg * 4 + i][k];
            acc[i][0] += f * w.x; acc[i][1] += f * w.y;
            acc[i][2] += f * w.z; acc[i][3] += f * w.w;
        }
    }
    #pragma unroll
    for (int i = 0; i < 4; ++i) {
        float4 v;
        v.x = silu_f(acc[i][0]); v.y = silu_f(acc[i][1]);
        v.z = silu_f(acc[i][2]); v.w = silu_f(acc[i][3]);
        *(float4*)&h1s[eg * 4 + i][j0] = v;
    }
    __syncthreads();

    // ---- edge MLP layer 2: [128] -> [128], SiLU; scatter-add to aggr ----
    float acc2[4][4];
    {
        float4 b = *(const float4*)&eb2[j0];
        #pragma unroll
        for (int i = 0; i < 4; ++i) { acc2[i][0]=b.x; acc2[i][1]=b.y; acc2[i][2]=b.z; acc2[i][3]=b.w; }
    }
    for (int k = 0; k < D; ++k) {
        float4 w = *(const float4*)&eW2[k * D + j0];
        #pragma unroll
        for (int i = 0; i < 4; ++i) {
            float f = h1s[eg * 4 + i][k];
            acc2[i][0] += f * w.x; acc2[i][1] += f * w.y;
            acc2[i][2] += f * w.z; acc2[i][3] += f * w.w;
        }
    }
    float* msgs = &feat[0][0];   // reuse feat LDS: msgs[e*D + j] (feat dead now)
    #pragma unroll
    for (int i = 0; i < 4; ++i) {
        int e = eg * 4 + i;
        float m0 = silu_f(acc2[i][0]), m1 = silu_f(acc2[i][1]);
        float m2 = silu_f(acc2[i][2]), m3 = silu_f(acc2[i][3]);
        float4 v; v.x = m0; v.y = m1; v.z = m2; v.w = m3;
        *(float4*)&msgs[e * D + j0] = v;
        float* ap = &aggr[s_dst[e] * D + j0];
        atomicAdd(ap + 0, m0); atomicAdd(ap + 1, m1);
        atomicAdd(ap + 2, m2); atomicAdd(ap + 3, m3);
    }
    __syncthreads();

    // ---- coord MLP: [128] -> [64] SiLU -> [1]; scatter coord update ----
    // thread (eg, jg): edges eg*4..+3, hidden outputs jg*2, jg*2+1
    float c_acc[4][2];
    {
        float b0 = cb1[jg * 2], b1 = cb1[jg * 2 + 1];
        #pragma unroll
        for (int i = 0; i < 4; ++i) { c_acc[i][0] = b0; c_acc[i][1] = b1; }
    }
    for (int k = 0; k < D; ++k) {
        float w0 = cW1[k * 64 + jg * 2];
        float w1 = cW1[k * 64 + jg * 2 + 1];
        #pragma unroll
        for (int i = 0; i < 4; ++i) {
            float f = msgs[(eg * 4 + i) * D + k];
            c_acc[i][0] += f * w0; c_acc[i][1] += f * w1;
        }
    }
    float w2a = cW2[jg * 2], w2b = cW2[jg * 2 + 1];
    float part[4];
    #pragma unroll
    for (int i = 0; i < 4; ++i)
        part[i] = silu_f(c_acc[i][0]) * w2a + silu_f(c_acc[i][1]) * w2b;
    // reduce across the 32 jg lanes (tid = eg*32 + jg, so width-32 shuffles
    // reduce within one eg group)
    #pragma unroll
    for (int s = 16; s > 0; s >>= 1) {
        #pragma unroll
        for (int i = 0; i < 4; ++i) part[i] += __shfl_down(part[i], s, 32);
    }
    if (jg == 0) {
        float cb2v = cb2[0];
        #pragma unroll
        for (int i = 0; i < 4; ++i) {
            int e = eg * 4 + i;
            float wgt = part[i] + cb2v;
            int s = s_src[e], d = s_dst[e];
            float dx = coords[s * 3 + 0] - coords[d * 3 + 0];
            float dy = coords[s * 3 + 1] - coords[d * 3 + 1];
            float dz = coords[s * 3 + 2] - coords[d * 3 + 2];
            float inv = wgt / (sqrtf(dx * dx + dy * dy + dz * dz) + EPS);
            atomicAdd(&out_coords[d * 3 + 0], dx * inv);
            atomicAdd(&out_coords[d * 3 + 1], dy * inv);
            atomicAdd(&out_coords[d * 3 + 2], dz * inv);
        }
    }
}

// ---------------------------------------------------------------------------
// node kernel: node MLP (2 layers, residual). 32 nodes per block, 256 threads.
// ---------------------------------------------------------------------------
__global__ __launch_bounds__(256, 2)
void node_kernel(const float* __restrict__ node_feat,
                 const float* __restrict__ aggr,
                 const float* __restrict__ nW1, const float* __restrict__ nb1,
                 const float* __restrict__ nW2, const float* __restrict__ nb2,
                 float* __restrict__ out_nodes) {
    __shared__ float nf[TN][256];   // concat(node_feat, aggr)
    __shared__ float hh[TN][D];
    const int tid = threadIdx.x;
    const int N0 = blockIdx.x * TN;

    for (int idx = tid; idx < TN * D; idx += 256) {
        int i = idx >> 7, j = idx & 127;
        nf[i][j]       = node_feat[(N0 + i) * D + j];
        nf[i][128 + j] = aggr[(N0 + i) * D + j];
    }
    __syncthreads();

    const int eg = tid >> 5, jg = tid & 31, j0 = jg * 4;

    float acc[4][4];
    {
        float4 b = *(const float4*)&nb1[j0];
        #pragma unroll
        for (int i = 0; i < 4; ++i) { acc[i][0]=b.x; acc[i][1]=b.y; acc[i][2]=b.z; acc[i][3]=b.w; }
    }
    for (int k = 0; k < 256; ++k) {
        float4 w = *(const float4*)&nW1[k * D + j0];
        #pragma unroll
        for (int i = 0; i < 4; ++i) {
            float f = nf[eg * 4 + i][k];
            acc[i][0] += f * w.x; acc[i][1] += f * w.y;
            acc[i][2] += f * w.z; acc[i][3] += f * w.w;
        }
    }
    #pragma unroll
    for (int i = 0; i < 4; ++i) {
        float4 v;
        v.x = silu_f(acc[i][0]); v.y = silu_f(acc[i][1]);
        v.z = silu_f(acc[i][2]); v.w = silu_f(acc[i][3]);
        *(float4*)&hh[eg * 4 + i][j0] = v;
    }
    __syncthreads();

    float acc2[4][4];
    {
        float4 b = *(const float4*)&nb2[j0];
        #pragma unroll
        for (int i = 0; i < 4; ++i) { acc2[i][0]=b.x; acc2[i][1]=b.y; acc2[i][2]=b.z; acc2[i][3]=b.w; }
    }
    for (int k = 0; k < D; ++k) {
        float4 w = *(const float4*)&nW2[k * D + j0];
        #pragma unroll
        for (int i = 0; i < 4; ++i) {
            float f = hh[eg * 4 + i][k];
            acc2[i][0] += f * w.x; acc2[i][1] += f * w.y;
            acc2[i][2] += f * w.z; acc2[i][3] += f * w.w;
        }
    }
    #pragma unroll
    for (int i = 0; i < 4; ++i) {
        int il = eg * 4 + i;
        int n = N0 + il;
        float4 o;
        o.x = acc2[i][0] + nf[il][j0 + 0];
        o.y = acc2[i][1] + nf[il][j0 + 1];
        o.z = acc2[i][2] + nf[il][j0 + 2];
        o.w = acc2[i][3] + nf[il][j0 + 3];
        *(float4*)&out_nodes[n * D + j0] = o;
    }
}

extern "C" void kernel_launch(void* const* d_in, const int* in_sizes, int n_in,
                              void* d_out, int out_size, void* d_ws, size_t ws_size,
                              hipStream_t stream) {
    const float* node_feat = (const float*)d_in[0];
    const int*   edge_index = (const int*)d_in[1];
    const float* edge_attr = (const float*)d_in[2];
    const float* coords    = (const float*)d_in[3];
    const float* eW1 = (const float*)d_in[4];
    const float* eb1 = (const float*)d_in[5];
    const float* eW2 = (const float*)d_in[6];
    const float* eb2 = (const float*)d_in[7];
    const float* nW1 = (const float*)d_in[8];
    const float* nb1 = (const float*)d_in[9];
    const float* nW2 = (const float*)d_in[10];
    const float* nb2 = (const float*)d_in[11];
    const float* cW1 = (const float*)d_in[12];
    const float* cb1 = (const float*)d_in[13];
    const float* cW2 = (const float*)d_in[14];
    const float* cb2 = (const float*)d_in[15];

    float* out_nodes  = (float*)d_out;
    float* out_coords = out_nodes + (size_t)N_NODES * D;
    float* aggr = (float*)d_ws;   // N_NODES * D floats = 10.24 MB

    init_kernel<<<512, 256, 0, stream>>>(coords, aggr, out_coords);
    edge_kernel<<<N_EDGES / TE, 256, 0, stream>>>(
        node_feat, edge_index, edge_attr, coords,
        eW1, eb1, eW2, eb2, cW1, cb1, cW2, cb2, aggr, out_coords);
    node_kernel<<<N_NODES / TN, 256, 0, stream>>>(
        node_feat, aggr, nW1, nb1, nW2, nb2, out_nodes);
}

// Round 3
// 778.335 us; speedup vs baseline: 3.0215x; 3.0215x over previous
//
#include <hip/hip_runtime.h>
#include <math.h>

#define N_NODES 20000
#define N_EDGES 640000
#define D 128      // NODE_DIM == HID
#define ED 64      // EDGE_DIM
#define EPS 1e-8f
#define MT 64      // edges per block (edge kernel)
#define TN 32      // nodes per block (node kernel)

#define FSTRIDE 328              // featA row stride (bf16 elems): 320 + 8 pad
#define HSTRIDE 136              // h1/msg row stride: 128 + 8 pad
#define MSG_OFF (MT * HSTRIDE)   // msg region: 8704..17408 shorts
#define LDS_SHORTS (MT * FSTRIDE)  // 20992 shorts = 41984 B (feat ⊇ h1+msg overlay)

typedef __attribute__((ext_vector_type(8))) short bf16x8;
typedef __attribute__((ext_vector_type(4))) float f32x4;

__device__ __forceinline__ float silu_f(float x) { return x / (1.0f + __expf(-x)); }

__device__ __forceinline__ short f2bf(float f) {   // RNE f32 -> bf16
    union { float f; unsigned u; } v; v.f = f;
    unsigned r = v.u + 0x7FFFu + ((v.u >> 16) & 1u);
    return (short)(r >> 16);
}
__device__ __forceinline__ float bf2f(short s) {
    union { unsigned u; float f; } v;
    v.u = ((unsigned)(unsigned short)s) << 16;
    return v.f;
}

// ---------------------------------------------------------------------------
// init: zero the node-output region (doubles as the message aggregation
// buffer), seed out_coords = coords. d_out is poisoned 0xAA before each call.
// ---------------------------------------------------------------------------
__global__ void init_kernel(const float* __restrict__ coords,
                            float* __restrict__ nodes_io,
                            float* __restrict__ out_coords) {
    int stride = gridDim.x * blockDim.x;
    int i = blockIdx.x * blockDim.x + threadIdx.x;
    for (int idx = i; idx < N_NODES * D; idx += stride) nodes_io[idx] = 0.0f;
    for (int idx = i; idx < N_NODES * 3; idx += stride) out_coords[idx] = coords[idx];
}

// ---------------------------------------------------------------------------
// prep: convert eW1/eW2/cW1 (f32 row-major [K][N]) into bf16 MFMA B-fragment
// order: frag f = (kc*NT + nt)*64 + lane holds 8 bf16:
//   B[kc*32 + (lane>>4)*8 + j][nt*16 + (lane&15)]   j = 0..7
// Total ws use: (40960 + 16384 + 8192) shorts = 131072 B  << ws_size.
// ---------------------------------------------------------------------------
__global__ void prep_kernel(const float* __restrict__ eW1,
                            const float* __restrict__ eW2,
                            const float* __restrict__ cW1,
                            short* __restrict__ eW1bf,
                            short* __restrict__ eW2bf,
                            short* __restrict__ cW1bf) {
    int t = blockIdx.x * blockDim.x + threadIdx.x;
    if (t < 5120) {                       // eW1: K=320 (10 kc), N=128 (8 nt)
        int f = t;
        int lane = f & 63, nt = (f >> 6) & 7, kc = f >> 9;
        int quad = lane >> 4, col = nt * 16 + (lane & 15);
        bf16x8 o;
        #pragma unroll
        for (int j = 0; j < 8; ++j)
            o[j] = f2bf(eW1[(kc * 32 + quad * 8 + j) * 128 + col]);
        *(bf16x8*)&eW1bf[f * 8] = o;
    } else if (t < 5120 + 2048) {         // eW2: K=128 (4 kc), N=128 (8 nt)
        int f = t - 5120;
        int lane = f & 63, nt = (f >> 6) & 7, kc = f >> 9;
        int quad = lane >> 4, col = nt * 16 + (lane & 15);
        bf16x8 o;
        #pragma unroll
        for (int j = 0; j < 8; ++j)
            o[j] = f2bf(eW2[(kc * 32 + quad * 8 + j) * 128 + col]);
        *(bf16x8*)&eW2bf[f * 8] = o;
    } else if (t < 8192) {                // cW1: K=128 (4 kc), N=64 (4 nt)
        int f = t - 7168;
        int lane = f & 63, nt = (f >> 6) & 3, kc = f >> 8;
        int quad = lane >> 4, col = nt * 16 + (lane & 15);
        bf16x8 o;
        #pragma unroll
        for (int j = 0; j < 8; ++j)
            o[j] = f2bf(cW1[(kc * 32 + quad * 8 + j) * 64 + col]);
        *(bf16x8*)&cW1bf[f * 8] = o;
    }
}

// ---------------------------------------------------------------------------
// edge kernel: MFMA edge-MLP (2 layers) + coord-MLP + scatters.
// 64 edges/block, 4 waves; wave w owns edges [w*16, w*16+16).
// LDS overlay: feat[0..20992) for GEMM1; after a barrier the same region is
// reused as h1[0..8704) and msg[8704..17408). 42 KB -> 3 blocks/CU.
// Message aggregation goes directly into the node-output region of d_out.
// ---------------------------------------------------------------------------
__global__ __launch_bounds__(256, 3)
void edge_kernel(const float* __restrict__ node_feat,
                 const int* __restrict__ edge_index,
                 const float* __restrict__ edge_attr,
                 const float* __restrict__ coords,
                 const float* __restrict__ eb1, const float* __restrict__ eb2,
                 const float* __restrict__ cb1, const float* __restrict__ cW2,
                 const float* __restrict__ cb2,
                 const short* __restrict__ eW1bf,
                 const short* __restrict__ eW2bf,
                 const short* __restrict__ cW1bf,
                 float* __restrict__ aggr_nodes, float* __restrict__ out_coords) {
    __shared__ __align__(16) short lds[LDS_SHORTS];
    __shared__ int s_src[MT], s_dst[MT];

    const int tid = threadIdx.x;
    const int E0 = blockIdx.x * MT;

    if (tid < MT) {
        s_src[tid] = edge_index[E0 + tid];
        s_dst[tid] = edge_index[N_EDGES + E0 + tid];
    }
    __syncthreads();

    // ---- stage A1 = concat(nf[src], nf[dst], ea) as bf16 into LDS ----
    {
        int e = tid >> 2, p = tid & 3;           // 4 threads/edge, 32 elems each
        const float* srow = node_feat + (size_t)s_src[e] * D + p * 32;
        const float* drow = node_feat + (size_t)s_dst[e] * D + p * 32;
        short* frow = &lds[e * FSTRIDE];
        #pragma unroll
        for (int c = 0; c < 4; ++c) {
            float4 f0 = *(const float4*)&srow[c * 8];
            float4 f1 = *(const float4*)&srow[c * 8 + 4];
            bf16x8 pk;
            pk[0]=f2bf(f0.x); pk[1]=f2bf(f0.y); pk[2]=f2bf(f0.z); pk[3]=f2bf(f0.w);
            pk[4]=f2bf(f1.x); pk[5]=f2bf(f1.y); pk[6]=f2bf(f1.z); pk[7]=f2bf(f1.w);
            *(bf16x8*)&frow[p * 32 + c * 8] = pk;
        }
        #pragma unroll
        for (int c = 0; c < 4; ++c) {
            float4 f0 = *(const float4*)&drow[c * 8];
            float4 f1 = *(const float4*)&drow[c * 8 + 4];
            bf16x8 pk;
            pk[0]=f2bf(f0.x); pk[1]=f2bf(f0.y); pk[2]=f2bf(f0.z); pk[3]=f2bf(f0.w);
            pk[4]=f2bf(f1.x); pk[5]=f2bf(f1.y); pk[6]=f2bf(f1.z); pk[7]=f2bf(f1.w);
            *(bf16x8*)&frow[128 + p * 32 + c * 8] = pk;
        }
        const float* arow = edge_attr + (size_t)(E0 + e) * ED + p * 16;
        #pragma unroll
        for (int c = 0; c < 2; ++c) {
            float4 f0 = *(const float4*)&arow[c * 8];
            float4 f1 = *(const float4*)&arow[c * 8 + 4];
            bf16x8 pk;
            pk[0]=f2bf(f0.x); pk[1]=f2bf(f0.y); pk[2]=f2bf(f0.z); pk[3]=f2bf(f0.w);
            pk[4]=f2bf(f1.x); pk[5]=f2bf(f1.y); pk[6]=f2bf(f1.z); pk[7]=f2bf(f1.w);
            *(bf16x8*)&frow[256 + p * 16 + c * 8] = pk;
        }
    }
    __syncthreads();

    const int lane = tid & 63;
    const int wv = tid >> 6;
    const int m0 = wv * 16;          // this wave's edge rows
    const int l15 = lane & 15;
    const int quad = lane >> 4;

    // ---- GEMM1: h1 = silu(feat @ eW1 + eb1), K=320 (10 kc), N=128 (8 nt) ----
    {
        f32x4 acc[8];
        #pragma unroll
        for (int nt = 0; nt < 8; ++nt) acc[nt] = (f32x4){0.f, 0.f, 0.f, 0.f};
        const bf16x8* W = (const bf16x8*)eW1bf;
        for (int kc = 0; kc < 10; ++kc) {
            bf16x8 a = *(const bf16x8*)&lds[(m0 + l15) * FSTRIDE + kc * 32 + quad * 8];
            #pragma unroll
            for (int nt = 0; nt < 8; ++nt) {
                bf16x8 b = W[(kc * 8 + nt) * 64 + lane];
                acc[nt] = __builtin_amdgcn_mfma_f32_16x16x32_bf16(a, b, acc[nt], 0, 0, 0);
            }
        }
        __syncthreads();   // all waves done reading feat; overlay h1 on it
        #pragma unroll
        for (int nt = 0; nt < 8; ++nt) {
            int n = nt * 16 + l15;                 // D: col = lane&15
            float bb = eb1[n];
            #pragma unroll
            for (int r = 0; r < 4; ++r) {
                int m = quad * 4 + r;              // D: row = quad*4 + reg
                lds[(m0 + m) * HSTRIDE + n] = f2bf(silu_f(acc[nt][r] + bb));
            }
        }
    }
    __syncthreads();

    // ---- GEMM2: msg = silu(h1 @ eW2 + eb2), K=128 (4 kc), N=128 (8 nt) ----
    // h1 at lds[0..), msg at lds[MSG_OFF..) (disjoint regions, no barrier
    // needed between own reads and writes).
    {
        f32x4 acc[8];
        #pragma unroll
        for (int nt = 0; nt < 8; ++nt) acc[nt] = (f32x4){0.f, 0.f, 0.f, 0.f};
        const bf16x8* W = (const bf16x8*)eW2bf;
        for (int kc = 0; kc < 4; ++kc) {
            bf16x8 a = *(const bf16x8*)&lds[(m0 + l15) * HSTRIDE + kc * 32 + quad * 8];
            #pragma unroll
            for (int nt = 0; nt < 8; ++nt) {
                bf16x8 b = W[(kc * 8 + nt) * 64 + lane];
                acc[nt] = __builtin_amdgcn_mfma_f32_16x16x32_bf16(a, b, acc[nt], 0, 0, 0);
            }
        }
        #pragma unroll
        for (int nt = 0; nt < 8; ++nt) {
            int n = nt * 16 + l15;
            float bb = eb2[n];
            #pragma unroll
            for (int r = 0; r < 4; ++r) {
                int m = quad * 4 + r;
                lds[MSG_OFF + (m0 + m) * HSTRIDE + n] = f2bf(silu_f(acc[nt][r] + bb));
            }
        }
    }
    __syncthreads();

    // ---- GEMM3: h3 = silu(msg @ cW1 + cb1), K=128 (4 kc), N=64 (4 nt);
    //      w = h3 @ cW2 + cb2 per edge; coord update scatter. ----
    {
        f32x4 acc[4];
        #pragma unroll
        for (int nt = 0; nt < 4; ++nt) acc[nt] = (f32x4){0.f, 0.f, 0.f, 0.f};
        const bf16x8* W = (const bf16x8*)cW1bf;
        for (int kc = 0; kc < 4; ++kc) {
            bf16x8 a = *(const bf16x8*)&lds[MSG_OFF + (m0 + l15) * HSTRIDE + kc * 32 + quad * 8];
            #pragma unroll
            for (int nt = 0; nt < 4; ++nt) {
                bf16x8 b = W[(kc * 4 + nt) * 64 + lane];
                acc[nt] = __builtin_amdgcn_mfma_f32_16x16x32_bf16(a, b, acc[nt], 0, 0, 0);
            }
        }
        float part[4] = {0.f, 0.f, 0.f, 0.f};
        #pragma unroll
        for (int nt = 0; nt < 4; ++nt) {
            int n = nt * 16 + l15;
            float b1v = cb1[n], w2v = cW2[n];
            #pragma unroll
            for (int r = 0; r < 4; ++r)
                part[r] += silu_f(acc[nt][r] + b1v) * w2v;
        }
        // reduce across the 16 lanes of each quad (rows m = quad*4 + r)
        #pragma unroll
        for (int s = 1; s < 16; s <<= 1) {
            #pragma unroll
            for (int r = 0; r < 4; ++r) part[r] += __shfl_xor(part[r], s, 64);
        }
        if (l15 == 0) {
            float cb2v = cb2[0];
            #pragma unroll
            for (int r = 0; r < 4; ++r) {
                int e = m0 + quad * 4 + r;
                float wgt = part[r] + cb2v;
                int s = s_src[e], d = s_dst[e];
                float dx = coords[s * 3 + 0] - coords[d * 3 + 0];
                float dy = coords[s * 3 + 1] - coords[d * 3 + 1];
                float dz = coords[s * 3 + 2] - coords[d * 3 + 2];
                float inv = wgt / (sqrtf(dx * dx + dy * dy + dz * dz) + EPS);
                unsafeAtomicAdd(&out_coords[d * 3 + 0], dx * inv);
                unsafeAtomicAdd(&out_coords[d * 3 + 1], dy * inv);
                unsafeAtomicAdd(&out_coords[d * 3 + 2], dz * inv);
            }
        }
    }

    // ---- message scatter into the node-output region (zeroed by init);
    // coalesced consecutive-address atomics, fire-and-forget (drain at
    // kernel end; node_kernel is stream-ordered after us).
    for (int idx = tid; idx < MT * D; idx += 256) {
        int e = idx >> 7, n = idx & 127;
        float v = bf2f(lds[MSG_OFF + e * HSTRIDE + n]);
        unsafeAtomicAdd(&aggr_nodes[(size_t)s_dst[e] * D + n], v);
    }
}

// ---------------------------------------------------------------------------
// node kernel: node MLP (2 layers, residual), fp32. 32 nodes/block.
// nodes_io holds aggregated messages on entry; overwritten in place with the
// final node output (each block owns its 32 rows exclusively).
// ---------------------------------------------------------------------------
__global__ __launch_bounds__(256, 2)
void node_kernel(const float* __restrict__ node_feat,
                 float* nodes_io,
                 const float* __restrict__ nW1, const float* __restrict__ nb1,
                 const float* __restrict__ nW2, const float* __restrict__ nb2) {
    __shared__ float nf[TN][256];
    __shared__ float hh[TN][D];
    const int tid = threadIdx.x;
    const int N0 = blockIdx.x * TN;

    for (int idx = tid; idx < TN * D; idx += 256) {
        int i = idx >> 7, j = idx & 127;
        nf[i][j]       = node_feat[(N0 + i) * D + j];
        nf[i][128 + j] = nodes_io[(N0 + i) * D + j];   // aggr
    }
    __syncthreads();

    const int eg = tid >> 5, jg = tid & 31, j0 = jg * 4;

    float acc[4][4];
    {
        float4 b = *(const float4*)&nb1[j0];
        #pragma unroll
        for (int i = 0; i < 4; ++i) { acc[i][0]=b.x; acc[i][1]=b.y; acc[i][2]=b.z; acc[i][3]=b.w; }
    }
    for (int k = 0; k < 256; ++k) {
        float4 w = *(const float4*)&nW1[k * D + j0];
        #pragma unroll
        for (int i = 0; i < 4; ++i) {
            float f = nf[eg * 4 + i][k];
            acc[i][0] += f * w.x; acc[i][1] += f * w.y;
            acc[i][2] += f * w.z; acc[i][3] += f * w.w;
        }
    }
    #pragma unroll
    for (int i = 0; i < 4; ++i) {
        float4 v;
        v.x = silu_f(acc[i][0]); v.y = silu_f(acc[i][1]);
        v.z = silu_f(acc[i][2]); v.w = silu_f(acc[i][3]);
        *(float4*)&hh[eg * 4 + i][j0] = v;
    }
    __syncthreads();

    float acc2[4][4];
    {
        float4 b = *(const float4*)&nb2[j0];
        #pragma unroll
        for (int i = 0; i < 4; ++i) { acc2[i][0]=b.x; acc2[i][1]=b.y; acc2[i][2]=b.z; acc2[i][3]=b.w; }
    }
    for (int k = 0; k < D; ++k) {
        float4 w = *(const float4*)&nW2[k * D + j0];
        #pragma unroll
        for (int i = 0; i < 4; ++i) {
            float f = hh[eg * 4 + i][k];
            acc2[i][0] += f * w.x; acc2[i][1] += f * w.y;
            acc2[i][2] += f * w.z; acc2[i][3] += f * w.w;
        }
    }
    #pragma unroll
    for (int i = 0; i < 4; ++i) {
        int il = eg * 4 + i;
        int n = N0 + il;
        float4 o;
        o.x = acc2[i][0] + nf[il][j0 + 0];
        o.y = acc2[i][1] + nf[il][j0 + 1];
        o.z = acc2[i][2] + nf[il][j0 + 2];
        o.w = acc2[i][3] + nf[il][j0 + 3];
        *(float4*)&nodes_io[n * D + j0] = o;
    }
}

extern "C" void kernel_launch(void* const* d_in, const int* in_sizes, int n_in,
                              void* d_out, int out_size, void* d_ws, size_t ws_size,
                              hipStream_t stream) {
    const float* node_feat  = (const float*)d_in[0];
    const int*   edge_index = (const int*)d_in[1];
    const float* edge_attr  = (const float*)d_in[2];
    const float* coords     = (const float*)d_in[3];
    const float* eW1 = (const float*)d_in[4];
    const float* eb1 = (const float*)d_in[5];
    const float* eW2 = (const float*)d_in[6];
    const float* eb2 = (const float*)d_in[7];
    const float* nW1 = (const float*)d_in[8];
    const float* nb1 = (const float*)d_in[9];
    const float* nW2 = (const float*)d_in[10];
    const float* nb2 = (const float*)d_in[11];
    const float* cW1 = (const float*)d_in[12];
    const float* cb1 = (const float*)d_in[13];
    const float* cW2 = (const float*)d_in[14];
    const float* cb2 = (const float*)d_in[15];

    float* nodes_io   = (float*)d_out;                      // aggr, then output
    float* out_coords = nodes_io + (size_t)N_NODES * D;

    // workspace: ONLY the swizzled weights (131072 B total).
    short* wbase = (short*)d_ws;
    short* eW1bf = wbase;
    short* eW2bf = wbase + 40960;
    short* cW1bf = wbase + 40960 + 16384;

    init_kernel<<<1024, 256, 0, stream>>>(coords, nodes_io, out_coords);
    prep_kernel<<<32, 256, 0, stream>>>(eW1, eW2, cW1, eW1bf, eW2bf, cW1bf);
    edge_kernel<<<N_EDGES / MT, 256, 0, stream>>>(
        node_feat, edge_index, edge_attr, coords,
        eb1, eb2, cb1, cW2, cb2, eW1bf, eW2bf, cW1bf, nodes_io, out_coords);
    node_kernel<<<N_NODES / TN, 256, 0, stream>>>(
        node_feat, nodes_io, nW1, nb1, nW2, nb2);
}

// Round 4
// 661.518 us; speedup vs baseline: 3.5551x; 1.1766x over previous
//
#include <hip/hip_runtime.h>
#include <math.h>

#define N_NODES 20000
#define N_EDGES 640000
#define D 128      // NODE_DIM == HID
#define ED 64      // EDGE_DIM
#define EPS 1e-8f
#define MT 64      // rows (edges/nodes) per block

#define FSTRIDE 328              // edge featA row stride (bf16): 320 + 8 pad
#define HSTRIDE 136              // h1/msg row stride: 128 + 8 pad
#define MSG_OFF (MT * HSTRIDE)   // msg region offset in shorts
#define LDS_SHORTS (MT * FSTRIDE)  // 20992 shorts = 41984 B

#define NSTRIDE 264              // node featA row stride: 256 + 8 pad

// swizzled-weight layout in d_ws (shorts):
//   eW1f @ 0      (80 frags)   eW2f @ 40960 (32)   cW1f @ 57344 (16)
//   nW1f @ 65536  (64)         nW2f @ 98304 (32)      [frag = 512 shorts]
#define EW2_OFF 40960
#define CW1_OFF 57344
#define NW1_OFF 65536
#define NW2_OFF 98304

typedef __attribute__((ext_vector_type(8))) short bf16x8;
typedef __attribute__((ext_vector_type(16))) float f32x16;

__device__ __forceinline__ float silu_f(float x) { return x / (1.0f + __expf(-x)); }

__device__ __forceinline__ short f2bf(float f) {   // RNE f32 -> bf16
    union { float f; unsigned u; } v; v.f = f;
    unsigned r = v.u + 0x7FFFu + ((v.u >> 16) & 1u);
    return (short)(r >> 16);
}
__device__ __forceinline__ float bf2f(short s) {
    union { unsigned u; float f; } v;
    v.u = ((unsigned)(unsigned short)s) << 16;
    return v.f;
}

// ---------------------------------------------------------------------------
// prep: swizzle all weight matrices (f32 row-major [K][N]) into 32x32x16
// B-fragment order. Frag (kc, nt), lane l, j=0..7 holds
//   W[kc*16 + (l>>5)*8 + j][nt*32 + (l&31)]
// ---------------------------------------------------------------------------
__global__ void prep_kernel(const float* __restrict__ eW1,
                            const float* __restrict__ eW2,
                            const float* __restrict__ cW1,
                            const float* __restrict__ nW1,
                            const float* __restrict__ nW2,
                            short* __restrict__ wsf) {
    int t = blockIdx.x * blockDim.x + threadIdx.x;
    if (t >= 224 * 64) return;
    int f = t >> 6, lane = t & 63;
    const float* src; int kc, nt, ncol; size_t dst;
    if (f < 80)       {              src = eW1; kc = f >> 2;  nt = f & 3;  ncol = 128; dst = (size_t)f * 512; }
    else if (f < 112) { int g=f-80;  src = eW2; kc = g >> 2;  nt = g & 3;  ncol = 128; dst = EW2_OFF + (size_t)g * 512; }
    else if (f < 128) { int g=f-112; src = cW1; kc = g >> 1;  nt = g & 1;  ncol = 64;  dst = CW1_OFF + (size_t)g * 512; }
    else if (f < 192) { int g=f-128; src = nW1; kc = g >> 2;  nt = g & 3;  ncol = 128; dst = NW1_OFF + (size_t)g * 512; }
    else              { int g=f-192; src = nW2; kc = g >> 2;  nt = g & 3;  ncol = 128; dst = NW2_OFF + (size_t)g * 512; }
    int col = nt * 32 + (lane & 31);
    int k0  = kc * 16 + (lane >> 5) * 8;
    bf16x8 o;
    #pragma unroll
    for (int j = 0; j < 8; ++j) o[j] = f2bf(src[(size_t)(k0 + j) * ncol + col]);
    *(bf16x8*)&wsf[dst + (size_t)lane * 8] = o;
}

// ---------------------------------------------------------------------------
// edge kernel: 64 edges/block, 4 waves. Wave wv: rows m0=(wv>>1)*32,
// N-half (wv&1). 32x32x16 bf16 MFMA. LDS overlay: feat[0..20992) for GEMM1,
// then h1[0..8704) + msg[8704..17408).
// ---------------------------------------------------------------------------
__global__ __launch_bounds__(256, 3)
void edge_kernel(const float* __restrict__ node_feat,
                 const int* __restrict__ edge_index,
                 const float* __restrict__ edge_attr,
                 const float* __restrict__ coords,
                 const float* __restrict__ eb1, const float* __restrict__ eb2,
                 const float* __restrict__ cb1, const float* __restrict__ cW2,
                 const float* __restrict__ cb2,
                 const short* __restrict__ wsf,
                 float* __restrict__ aggr_nodes, float* __restrict__ out_coords) {
    __shared__ __align__(16) short lds[LDS_SHORTS];
    __shared__ int s_src[MT], s_dst[MT];
    __shared__ float s_wgt[MT];

    const int tid = threadIdx.x;
    const int E0 = blockIdx.x * MT;

    // ---- stage A1 = concat(nf[src], nf[dst], ea) as bf16; indices inline ----
    {
        int e = tid >> 2, p = tid & 3;           // 4 threads/edge, 80 elems each
        int esrc = edge_index[E0 + e];
        int edst = edge_index[N_EDGES + E0 + e];
        if (p == 0) { s_src[e] = esrc; s_dst[e] = edst; }
        const float* srow = node_feat + (size_t)esrc * D + p * 32;
        const float* drow = node_feat + (size_t)edst * D + p * 32;
        short* frow = &lds[e * FSTRIDE];
        #pragma unroll
        for (int c = 0; c < 4; ++c) {
            float4 f0 = *(const float4*)&srow[c * 8];
            float4 f1 = *(const float4*)&srow[c * 8 + 4];
            bf16x8 pk;
            pk[0]=f2bf(f0.x); pk[1]=f2bf(f0.y); pk[2]=f2bf(f0.z); pk[3]=f2bf(f0.w);
            pk[4]=f2bf(f1.x); pk[5]=f2bf(f1.y); pk[6]=f2bf(f1.z); pk[7]=f2bf(f1.w);
            *(bf16x8*)&frow[p * 32 + c * 8] = pk;
        }
        #pragma unroll
        for (int c = 0; c < 4; ++c) {
            float4 f0 = *(const float4*)&drow[c * 8];
            float4 f1 = *(const float4*)&drow[c * 8 + 4];
            bf16x8 pk;
            pk[0]=f2bf(f0.x); pk[1]=f2bf(f0.y); pk[2]=f2bf(f0.z); pk[3]=f2bf(f0.w);
            pk[4]=f2bf(f1.x); pk[5]=f2bf(f1.y); pk[6]=f2bf(f1.z); pk[7]=f2bf(f1.w);
            *(bf16x8*)&frow[128 + p * 32 + c * 8] = pk;
        }
        const float* arow = edge_attr + (size_t)(E0 + e) * ED + p * 16;
        #pragma unroll
        for (int c = 0; c < 2; ++c) {
            float4 f0 = *(const float4*)&arow[c * 8];
            float4 f1 = *(const float4*)&arow[c * 8 + 4];
            bf16x8 pk;
            pk[0]=f2bf(f0.x); pk[1]=f2bf(f0.y); pk[2]=f2bf(f0.z); pk[3]=f2bf(f0.w);
            pk[4]=f2bf(f1.x); pk[5]=f2bf(f1.y); pk[6]=f2bf(f1.z); pk[7]=f2bf(f1.w);
            *(bf16x8*)&frow[256 + p * 16 + c * 8] = pk;
        }
    }
    __syncthreads();

    const int lane  = tid & 63;
    const int wv    = tid >> 6;
    const int m0    = (wv >> 1) * 32;     // this wave's 32 edge rows
    const int n0q   = wv & 1;             // N half (0: cols 0-63, 1: 64-127)
    const int l31   = lane & 31;
    const int khalf = lane >> 5;

    const bf16x8* W1 = (const bf16x8*)wsf;
    const bf16x8* W2 = (const bf16x8*)(wsf + EW2_OFF);
    const bf16x8* W3 = (const bf16x8*)(wsf + CW1_OFF);

    // ---- GEMM1: h1 = silu(feat @ eW1 + eb1), K=320 (20 kc), wave: 2 nt ----
    {
        f32x16 acc0, acc1;
        #pragma unroll
        for (int r = 0; r < 16; ++r) { acc0[r] = 0.f; acc1[r] = 0.f; }
        for (int kc = 0; kc < 20; ++kc) {
            bf16x8 a  = *(const bf16x8*)&lds[(m0 + l31) * FSTRIDE + kc * 16 + khalf * 8];
            bf16x8 b0 = W1[(kc * 4 + n0q * 2 + 0) * 64 + lane];
            bf16x8 b1 = W1[(kc * 4 + n0q * 2 + 1) * 64 + lane];
            acc0 = __builtin_amdgcn_mfma_f32_32x32x16_bf16(a, b0, acc0, 0, 0, 0);
            acc1 = __builtin_amdgcn_mfma_f32_32x32x16_bf16(a, b1, acc1, 0, 0, 0);
        }
        __syncthreads();   // all waves done reading feat; overlay h1
        #pragma unroll
        for (int nt = 0; nt < 2; ++nt) {
            f32x16 A = nt ? acc1 : acc0;
            int n = n0q * 64 + nt * 32 + l31;
            float bb = eb1[n];
            #pragma unroll
            for (int r = 0; r < 16; ++r) {
                int row = (r & 3) + 8 * (r >> 2) + 4 * khalf;
                lds[(m0 + row) * HSTRIDE + n] = f2bf(silu_f(A[r] + bb));
            }
        }
    }
    __syncthreads();

    // ---- GEMM2: msg = silu(h1 @ eW2 + eb2), K=128 (8 kc) ----
    {
        f32x16 acc0, acc1;
        #pragma unroll
        for (int r = 0; r < 16; ++r) { acc0[r] = 0.f; acc1[r] = 0.f; }
        for (int kc = 0; kc < 8; ++kc) {
            bf16x8 a  = *(const bf16x8*)&lds[(m0 + l31) * HSTRIDE + kc * 16 + khalf * 8];
            bf16x8 b0 = W2[(kc * 4 + n0q * 2 + 0) * 64 + lane];
            bf16x8 b1 = W2[(kc * 4 + n0q * 2 + 1) * 64 + lane];
            acc0 = __builtin_amdgcn_mfma_f32_32x32x16_bf16(a, b0, acc0, 0, 0, 0);
            acc1 = __builtin_amdgcn_mfma_f32_32x32x16_bf16(a, b1, acc1, 0, 0, 0);
        }
        #pragma unroll
        for (int nt = 0; nt < 2; ++nt) {
            f32x16 A = nt ? acc1 : acc0;
            int n = n0q * 64 + nt * 32 + l31;
            float bb = eb2[n];
            #pragma unroll
            for (int r = 0; r < 16; ++r) {
                int row = (r & 3) + 8 * (r >> 2) + 4 * khalf;
                lds[MSG_OFF + (m0 + row) * HSTRIDE + n] = f2bf(silu_f(A[r] + bb));
            }
        }
    }
    __syncthreads();

    // ---- GEMM3: h3 = silu(msg @ cW1 + cb1) [K=128, N=64, full per wave];
    //      per-edge weight = h3 @ cW2 + cb2 via lane reduction ----
    {
        f32x16 c0, c1;
        #pragma unroll
        for (int r = 0; r < 16; ++r) { c0[r] = 0.f; c1[r] = 0.f; }
        for (int kc = 0; kc < 8; ++kc) {
            bf16x8 a  = *(const bf16x8*)&lds[MSG_OFF + (m0 + l31) * HSTRIDE + kc * 16 + khalf * 8];
            bf16x8 b0 = W3[(kc * 2 + 0) * 64 + lane];
            bf16x8 b1 = W3[(kc * 2 + 1) * 64 + lane];
            c0 = __builtin_amdgcn_mfma_f32_32x32x16_bf16(a, b0, c0, 0, 0, 0);
            c1 = __builtin_amdgcn_mfma_f32_32x32x16_bf16(a, b1, c1, 0, 0, 0);
        }
        float b1a = cb1[l31], b1b = cb1[32 + l31];
        float w2a = cW2[l31], w2b = cW2[32 + l31];
        float part[16];
        #pragma unroll
        for (int r = 0; r < 16; ++r)
            part[r] = silu_f(c0[r] + b1a) * w2a + silu_f(c1[r] + b1b) * w2b;
        #pragma unroll
        for (int s = 1; s < 32; s <<= 1) {
            #pragma unroll
            for (int r = 0; r < 16; ++r) part[r] += __shfl_xor(part[r], s, 64);
        }
        if (l31 == 0) {
            float cb2v = cb2[0];
            #pragma unroll
            for (int r = 0; r < 16; ++r)
                s_wgt[m0 + (r & 3) + 8 * (r >> 2) + 4 * khalf] = part[r] + cb2v;
        }
    }
    __syncthreads();

    // ---- coord scatter (one thread/edge) ----
    if (tid < MT) {
        int e = tid;
        float wgt = s_wgt[e];
        int s = s_src[e], d = s_dst[e];
        float dx = coords[s * 3 + 0] - coords[d * 3 + 0];
        float dy = coords[s * 3 + 1] - coords[d * 3 + 1];
        float dz = coords[s * 3 + 2] - coords[d * 3 + 2];
        float inv = wgt / (sqrtf(dx * dx + dy * dy + dz * dz) + EPS);
        unsafeAtomicAdd(&out_coords[d * 3 + 0], dx * inv);
        unsafeAtomicAdd(&out_coords[d * 3 + 1], dy * inv);
        unsafeAtomicAdd(&out_coords[d * 3 + 2], dz * inv);
    }

    // ---- message scatter into node-output region (zeroed before launch) ----
    for (int idx = tid; idx < MT * D; idx += 256) {
        int e = idx >> 7, n = idx & 127;
        float v = bf2f(lds[MSG_OFF + e * HSTRIDE + n]);
        unsafeAtomicAdd(&aggr_nodes[(size_t)s_dst[e] * D + n], v);
    }
}

// ---------------------------------------------------------------------------
// node kernel (MFMA): 64 nodes/block. A = concat(node_feat, aggr) bf16;
// GEMM1 K=256 -> silu -> GEMM2 K=128 -> +bias +residual -> store fp32.
// nodes_io holds aggr on entry, final node output on exit (in place).
// ---------------------------------------------------------------------------
__global__ __launch_bounds__(256, 4)
void node_kernel(const float* __restrict__ node_feat,
                 float* nodes_io,
                 const float* __restrict__ nb1, const float* __restrict__ nb2,
                 const short* __restrict__ wsf) {
    __shared__ __align__(16) short lds[MT * NSTRIDE];   // 33792 B
    const int tid = threadIdx.x;
    const int N0 = blockIdx.x * MT;

    {
        int i = tid >> 2, p = tid & 3;
        int nid = N0 + i; if (nid > N_NODES - 1) nid = N_NODES - 1;
        const float* frow = node_feat + (size_t)nid * D + p * 32;
        const float* arow = nodes_io + (size_t)nid * D + p * 32;
        short* drow = &lds[i * NSTRIDE];
        #pragma unroll
        for (int c = 0; c < 4; ++c) {
            float4 f0 = *(const float4*)&frow[c * 8];
            float4 f1 = *(const float4*)&frow[c * 8 + 4];
            bf16x8 pk;
            pk[0]=f2bf(f0.x); pk[1]=f2bf(f0.y); pk[2]=f2bf(f0.z); pk[3]=f2bf(f0.w);
            pk[4]=f2bf(f1.x); pk[5]=f2bf(f1.y); pk[6]=f2bf(f1.z); pk[7]=f2bf(f1.w);
            *(bf16x8*)&drow[p * 32 + c * 8] = pk;
        }
        #pragma unroll
        for (int c = 0; c < 4; ++c) {
            float4 f0 = *(const float4*)&arow[c * 8];
            float4 f1 = *(const float4*)&arow[c * 8 + 4];
            bf16x8 pk;
            pk[0]=f2bf(f0.x); pk[1]=f2bf(f0.y); pk[2]=f2bf(f0.z); pk[3]=f2bf(f0.w);
            pk[4]=f2bf(f1.x); pk[5]=f2bf(f1.y); pk[6]=f2bf(f1.z); pk[7]=f2bf(f1.w);
            *(bf16x8*)&drow[128 + p * 32 + c * 8] = pk;
        }
    }
    __syncthreads();

    const int lane  = tid & 63;
    const int wv    = tid >> 6;
    const int m0    = (wv >> 1) * 32;
    const int n0q   = wv & 1;
    const int l31   = lane & 31;
    const int khalf = lane >> 5;

    const bf16x8* W1 = (const bf16x8*)(wsf + NW1_OFF);
    const bf16x8* W2 = (const bf16x8*)(wsf + NW2_OFF);

    // ---- GEMM1: K=256 (16 kc) ----
    {
        f32x16 acc0, acc1;
        #pragma unroll
        for (int r = 0; r < 16; ++r) { acc0[r] = 0.f; acc1[r] = 0.f; }
        for (int kc = 0; kc < 16; ++kc) {
            bf16x8 a  = *(const bf16x8*)&lds[(m0 + l31) * NSTRIDE + kc * 16 + khalf * 8];
            bf16x8 b0 = W1[(kc * 4 + n0q * 2 + 0) * 64 + lane];
            bf16x8 b1 = W1[(kc * 4 + n0q * 2 + 1) * 64 + lane];
            acc0 = __builtin_amdgcn_mfma_f32_32x32x16_bf16(a, b0, acc0, 0, 0, 0);
            acc1 = __builtin_amdgcn_mfma_f32_32x32x16_bf16(a, b1, acc1, 0, 0, 0);
        }
        __syncthreads();
        #pragma unroll
        for (int nt = 0; nt < 2; ++nt) {
            f32x16 A = nt ? acc1 : acc0;
            int n = n0q * 64 + nt * 32 + l31;
            float bb = nb1[n];
            #pragma unroll
            for (int r = 0; r < 16; ++r) {
                int row = (r & 3) + 8 * (r >> 2) + 4 * khalf;
                lds[(m0 + row) * HSTRIDE + n] = f2bf(silu_f(A[r] + bb));
            }
        }
    }
    __syncthreads();

    // ---- GEMM2: K=128 (8 kc); +bias +residual; store fp32 ----
    {
        f32x16 acc0, acc1;
        #pragma unroll
        for (int r = 0; r < 16; ++r) { acc0[r] = 0.f; acc1[r] = 0.f; }
        for (int kc = 0; kc < 8; ++kc) {
            bf16x8 a  = *(const bf16x8*)&lds[(m0 + l31) * HSTRIDE + kc * 16 + khalf * 8];
            bf16x8 b0 = W2[(kc * 4 + n0q * 2 + 0) * 64 + lane];
            bf16x8 b1 = W2[(kc * 4 + n0q * 2 + 1) * 64 + lane];
            acc0 = __builtin_amdgcn_mfma_f32_32x32x16_bf16(a, b0, acc0, 0, 0, 0);
            acc1 = __builtin_amdgcn_mfma_f32_32x32x16_bf16(a, b1, acc1, 0, 0, 0);
        }
        #pragma unroll
        for (int nt = 0; nt < 2; ++nt) {
            f32x16 A = nt ? acc1 : acc0;
            int n = n0q * 64 + nt * 32 + l31;
            float bb = nb2[n];
            #pragma unroll
            for (int r = 0; r < 16; ++r) {
                int row = (r & 3) + 8 * (r >> 2) + 4 * khalf;
                int nid = N0 + m0 + row;
                if (nid < N_NODES)
                    nodes_io[(size_t)nid * D + n] = A[r] + bb + node_feat[(size_t)nid * D + n];
            }
        }
    }
}

extern "C" void kernel_launch(void* const* d_in, const int* in_sizes, int n_in,
                              void* d_out, int out_size, void* d_ws, size_t ws_size,
                              hipStream_t stream) {
    const float* node_feat  = (const float*)d_in[0];
    const int*   edge_index = (const int*)d_in[1];
    const float* edge_attr  = (const float*)d_in[2];
    const float* coords     = (const float*)d_in[3];
    const float* eW1 = (const float*)d_in[4];
    const float* eb1 = (const float*)d_in[5];
    const float* eW2 = (const float*)d_in[6];
    const float* eb2 = (const float*)d_in[7];
    const float* nW1 = (const float*)d_in[8];
    const float* nb1 = (const float*)d_in[9];
    const float* nW2 = (const float*)d_in[10];
    const float* nb2 = (const float*)d_in[11];
    const float* cW1 = (const float*)d_in[12];
    const float* cb1 = (const float*)d_in[13];
    const float* cW2 = (const float*)d_in[14];
    const float* cb2 = (const float*)d_in[15];

    float* nodes_io   = (float*)d_out;                 // aggr, then node output
    float* out_coords = nodes_io + (size_t)N_NODES * D;
    short* wsf = (short*)d_ws;                         // 229376 B of swizzled W

    hipMemsetAsync(nodes_io, 0, (size_t)N_NODES * D * sizeof(float), stream);
    hipMemcpyAsync(out_coords, coords, (size_t)N_NODES * 3 * sizeof(float),
                   hipMemcpyDeviceToDevice, stream);
    prep_kernel<<<56, 256, 0, stream>>>(eW1, eW2, cW1, nW1, nW2, wsf);
    edge_kernel<<<N_EDGES / MT, 256, 0, stream>>>(
        node_feat, edge_index, edge_attr, coords,
        eb1, eb2, cb1, cW2, cb2, wsf, nodes_io, out_coords);
    node_kernel<<<(N_NODES + MT - 1) / MT, 256, 0, stream>>>(
        node_feat, nodes_io, nb1, nb2, wsf);
}

// Round 5
// 635.085 us; speedup vs baseline: 3.7030x; 1.0416x over previous
//
#include <hip/hip_runtime.h>
#include <math.h>

#define N_NODES 20000
#define N_EDGES 640000
#define D 128      // NODE_DIM == HID
#define ED 64      // EDGE_DIM
#define EPS 1e-8f
#define MT 64      // rows (edges/nodes) per block

#define FSTRIDE 328              // edge featA row stride (bf16): 320 + 8 pad
#define HSTRIDE 136              // h1/msg row stride: 128 + 8 pad
#define MSG_OFF (MT * HSTRIDE)   // msg region offset in shorts
#define LDS_SHORTS (MT * FSTRIDE)  // 20992 shorts = 41984 B

#define NSTRIDE 264              // node featA row stride: 256 + 8 pad

// d_ws layout (shorts): swizzled weights then bf16 node_feat
//   eW1f @ 0 (80 frags) | eW2f @ 40960 (32) | cW1f @ 57344 (16)
//   nW1f @ 65536 (64)   | nW2f @ 98304 (32) | nfbf @ 114688 (2.56M shorts)
// total 5,349,376 B  (Round-1 proved ws_size >= 10.24 MB)
#define EW2_OFF 40960
#define CW1_OFF 57344
#define NW1_OFF 65536
#define NW2_OFF 98304
#define NFBF_OFF 114688

typedef __attribute__((ext_vector_type(8))) short bf16x8;
typedef __attribute__((ext_vector_type(16))) float f32x16;
typedef __attribute__((ext_vector_type(2))) float f32x2;

__device__ __forceinline__ float silu_f(float x) { return x / (1.0f + __expf(-x)); }

__device__ __forceinline__ short f2bf(float f) {   // RNE f32 -> bf16
    union { float f; unsigned u; } v; v.f = f;
    unsigned r = v.u + 0x7FFFu + ((v.u >> 16) & 1u);
    return (short)(r >> 16);
}
__device__ __forceinline__ float bf2f(short s) {
    union { unsigned u; float f; } v;
    v.u = ((unsigned)(unsigned short)s) << 16;
    return v.f;
}

#define SWZ_ADD(x, imm) (x + __int_as_float( \
    __builtin_amdgcn_ds_swizzle(__float_as_int(x), imm)))

// ---------------------------------------------------------------------------
// prep: (A) swizzle all weights into 32x32x16 B-frag order; (B) node_feat ->
// bf16; (C) zero node-output/aggr region; (D) seed out_coords = coords.
// One dispatch, 256 blocks x 256 threads.
// ---------------------------------------------------------------------------
__global__ __launch_bounds__(256)
void prep_kernel(const float* __restrict__ eW1, const float* __restrict__ eW2,
                 const float* __restrict__ cW1, const float* __restrict__ nW1,
                 const float* __restrict__ nW2,
                 const float* __restrict__ node_feat,
                 const float* __restrict__ coords,
                 short* __restrict__ wsf, short* __restrict__ nfbf,
                 float* __restrict__ nodes_io, float* __restrict__ out_coords) {
    const int t = blockIdx.x * blockDim.x + threadIdx.x;
    const int nthr = gridDim.x * blockDim.x;

    // (A) weight swizzle: frag (kc,nt), lane l, j holds W[kc*16+(l>>5)*8+j][nt*32+(l&31)]
    if (t < 224 * 64) {
        int f = t >> 6, lane = t & 63;
        const float* src; int kc, nt, ncol; size_t dst;
        if (f < 80)       {              src = eW1; kc = f >> 2;  nt = f & 3;  ncol = 128; dst = (size_t)f * 512; }
        else if (f < 112) { int g=f-80;  src = eW2; kc = g >> 2;  nt = g & 3;  ncol = 128; dst = EW2_OFF + (size_t)g * 512; }
        else if (f < 128) { int g=f-112; src = cW1; kc = g >> 1;  nt = g & 1;  ncol = 64;  dst = CW1_OFF + (size_t)g * 512; }
        else if (f < 192) { int g=f-128; src = nW1; kc = g >> 2;  nt = g & 3;  ncol = 128; dst = NW1_OFF + (size_t)g * 512; }
        else              { int g=f-192; src = nW2; kc = g >> 2;  nt = g & 3;  ncol = 128; dst = NW2_OFF + (size_t)g * 512; }
        int col = nt * 32 + (lane & 31);
        int k0  = kc * 16 + (lane >> 5) * 8;
        bf16x8 o;
        #pragma unroll
        for (int j = 0; j < 8; ++j) o[j] = f2bf(src[(size_t)(k0 + j) * ncol + col]);
        *(bf16x8*)&wsf[dst + (size_t)lane * 8] = o;
    }
    // (B) node_feat -> bf16 (8 elems per chunk)
    for (int idx = t; idx < N_NODES * D / 8; idx += nthr) {
        const float* s = node_feat + (size_t)idx * 8;
        float4 f0 = *(const float4*)s, f1 = *(const float4*)(s + 4);
        bf16x8 pk;
        pk[0]=f2bf(f0.x); pk[1]=f2bf(f0.y); pk[2]=f2bf(f0.z); pk[3]=f2bf(f0.w);
        pk[4]=f2bf(f1.x); pk[5]=f2bf(f1.y); pk[6]=f2bf(f1.z); pk[7]=f2bf(f1.w);
        *(bf16x8*)&nfbf[(size_t)idx * 8] = pk;
    }
    // (C) zero aggr region
    for (int idx = t; idx < N_NODES * D / 4; idx += nthr) {
        float4 z; z.x = 0.f; z.y = 0.f; z.z = 0.f; z.w = 0.f;
        *(float4*)&nodes_io[(size_t)idx * 4] = z;
    }
    // (D) coords copy
    for (int idx = t; idx < N_NODES * 3; idx += nthr)
        out_coords[idx] = coords[idx];
}

// ---------------------------------------------------------------------------
// edge kernel: 64 edges/block, 4 waves. Wave wv: rows m0=(wv>>1)*32, N-half
// (wv&1). 32x32x16 bf16 MFMA. A staged from pre-converted bf16 node_feat
// (pure copy) + edge_attr (inline cvt). LDS overlay: feat for GEMM1, then
// h1 + msg. Messages scattered with packed v2f32 atomics into d_out.
// ---------------------------------------------------------------------------
__global__ __launch_bounds__(256, 3)
void edge_kernel(const short* __restrict__ nfbf,
                 const int* __restrict__ edge_index,
                 const float* __restrict__ edge_attr,
                 const float* __restrict__ coords,
                 const float* __restrict__ eb1, const float* __restrict__ eb2,
                 const float* __restrict__ cb1, const float* __restrict__ cW2,
                 const float* __restrict__ cb2,
                 const short* __restrict__ wsf,
                 float* __restrict__ aggr_nodes, float* __restrict__ out_coords) {
    __shared__ __align__(16) short lds[LDS_SHORTS];
    __shared__ int s_src[MT], s_dst[MT];
    __shared__ float s_wgt[MT];

    const int tid = threadIdx.x;
    const int E0 = blockIdx.x * MT;

    // ---- stage A1 = concat(nfbf[src], nfbf[dst], cvt(ea)) ----
    {
        int e = tid >> 2, p = tid & 3;           // 4 threads/edge
        int esrc = edge_index[E0 + e];
        int edst = edge_index[N_EDGES + E0 + e];
        if (p == 0) { s_src[e] = esrc; s_dst[e] = edst; }
        const short* srow = nfbf + (size_t)esrc * D;
        const short* drow = nfbf + (size_t)edst * D;
        short* frow = &lds[e * FSTRIDE];
        #pragma unroll
        for (int c = 0; c < 4; ++c)
            *(bf16x8*)&frow[c * 32 + p * 8] = *(const bf16x8*)&srow[c * 32 + p * 8];
        #pragma unroll
        for (int c = 0; c < 4; ++c)
            *(bf16x8*)&frow[128 + c * 32 + p * 8] = *(const bf16x8*)&drow[c * 32 + p * 8];
        const float* arow = edge_attr + (size_t)(E0 + e) * ED + p * 16;
        float4 a0 = *(const float4*)&arow[0], a1 = *(const float4*)&arow[4];
        float4 a2 = *(const float4*)&arow[8], a3 = *(const float4*)&arow[12];
        bf16x8 p0, p1;
        p0[0]=f2bf(a0.x); p0[1]=f2bf(a0.y); p0[2]=f2bf(a0.z); p0[3]=f2bf(a0.w);
        p0[4]=f2bf(a1.x); p0[5]=f2bf(a1.y); p0[6]=f2bf(a1.z); p0[7]=f2bf(a1.w);
        p1[0]=f2bf(a2.x); p1[1]=f2bf(a2.y); p1[2]=f2bf(a2.z); p1[3]=f2bf(a2.w);
        p1[4]=f2bf(a3.x); p1[5]=f2bf(a3.y); p1[6]=f2bf(a3.z); p1[7]=f2bf(a3.w);
        *(bf16x8*)&frow[256 + p * 16]     = p0;
        *(bf16x8*)&frow[256 + p * 16 + 8] = p1;
    }
    __syncthreads();

    const int lane  = tid & 63;
    const int wv    = tid >> 6;
    const int m0    = (wv >> 1) * 32;     // this wave's 32 edge rows
    const int n0q   = wv & 1;             // N half
    const int l31   = lane & 31;
    const int khalf = lane >> 5;

    const bf16x8* W1 = (const bf16x8*)wsf;
    const bf16x8* W2 = (const bf16x8*)(wsf + EW2_OFF);
    const bf16x8* W3 = (const bf16x8*)(wsf + CW1_OFF);

    // ---- GEMM1: h1 = silu(feat @ eW1 + eb1), K=320 (20 kc) ----
    {
        f32x16 acc0, acc1;
        #pragma unroll
        for (int r = 0; r < 16; ++r) { acc0[r] = 0.f; acc1[r] = 0.f; }
        #pragma unroll
        for (int kc = 0; kc < 20; ++kc) {
            bf16x8 a  = *(const bf16x8*)&lds[(m0 + l31) * FSTRIDE + kc * 16 + khalf * 8];
            bf16x8 b0 = W1[(kc * 4 + n0q * 2 + 0) * 64 + lane];
            bf16x8 b1 = W1[(kc * 4 + n0q * 2 + 1) * 64 + lane];
            acc0 = __builtin_amdgcn_mfma_f32_32x32x16_bf16(a, b0, acc0, 0, 0, 0);
            acc1 = __builtin_amdgcn_mfma_f32_32x32x16_bf16(a, b1, acc1, 0, 0, 0);
        }
        __syncthreads();   // all waves done reading feat; overlay h1
        #pragma unroll
        for (int nt = 0; nt < 2; ++nt) {
            f32x16 A = nt ? acc1 : acc0;
            int n = n0q * 64 + nt * 32 + l31;
            float bb = eb1[n];
            #pragma unroll
            for (int r = 0; r < 16; ++r) {
                int row = (r & 3) + 8 * (r >> 2) + 4 * khalf;
                lds[(m0 + row) * HSTRIDE + n] = f2bf(silu_f(A[r] + bb));
            }
        }
    }
    __syncthreads();

    // ---- GEMM2: msg = silu(h1 @ eW2 + eb2), K=128 (8 kc) ----
    {
        f32x16 acc0, acc1;
        #pragma unroll
        for (int r = 0; r < 16; ++r) { acc0[r] = 0.f; acc1[r] = 0.f; }
        #pragma unroll
        for (int kc = 0; kc < 8; ++kc) {
            bf16x8 a  = *(const bf16x8*)&lds[(m0 + l31) * HSTRIDE + kc * 16 + khalf * 8];
            bf16x8 b0 = W2[(kc * 4 + n0q * 2 + 0) * 64 + lane];
            bf16x8 b1 = W2[(kc * 4 + n0q * 2 + 1) * 64 + lane];
            acc0 = __builtin_amdgcn_mfma_f32_32x32x16_bf16(a, b0, acc0, 0, 0, 0);
            acc1 = __builtin_amdgcn_mfma_f32_32x32x16_bf16(a, b1, acc1, 0, 0, 0);
        }
        #pragma unroll
        for (int nt = 0; nt < 2; ++nt) {
            f32x16 A = nt ? acc1 : acc0;
            int n = n0q * 64 + nt * 32 + l31;
            float bb = eb2[n];
            #pragma unroll
            for (int r = 0; r < 16; ++r) {
                int row = (r & 3) + 8 * (r >> 2) + 4 * khalf;
                lds[MSG_OFF + (m0 + row) * HSTRIDE + n] = f2bf(silu_f(A[r] + bb));
            }
        }
    }
    __syncthreads();

    // ---- GEMM3: h3 = silu(msg @ cW1 + cb1); per-edge w = h3 @ cW2 + cb2 ----
    {
        f32x16 c0, c1;
        #pragma unroll
        for (int r = 0; r < 16; ++r) { c0[r] = 0.f; c1[r] = 0.f; }
        #pragma unroll
        for (int kc = 0; kc < 8; ++kc) {
            bf16x8 a  = *(const bf16x8*)&lds[MSG_OFF + (m0 + l31) * HSTRIDE + kc * 16 + khalf * 8];
            bf16x8 b0 = W3[(kc * 2 + 0) * 64 + lane];
            bf16x8 b1 = W3[(kc * 2 + 1) * 64 + lane];
            c0 = __builtin_amdgcn_mfma_f32_32x32x16_bf16(a, b0, c0, 0, 0, 0);
            c1 = __builtin_amdgcn_mfma_f32_32x32x16_bf16(a, b1, c1, 0, 0, 0);
        }
        float b1a = cb1[l31], b1b = cb1[32 + l31];
        float w2a = cW2[l31], w2b = cW2[32 + l31];
        float part[16];
        #pragma unroll
        for (int r = 0; r < 16; ++r)
            part[r] = silu_f(c0[r] + b1a) * w2a + silu_f(c1[r] + b1b) * w2b;
        // butterfly over the 32 lanes of each half (ds_swizzle: no addr VALU)
        #pragma unroll
        for (int r = 0; r < 16; ++r) {
            part[r] = SWZ_ADD(part[r], 0x041F);
            part[r] = SWZ_ADD(part[r], 0x081F);
            part[r] = SWZ_ADD(part[r], 0x101F);
            part[r] = SWZ_ADD(part[r], 0x201F);
            part[r] = SWZ_ADD(part[r], 0x401F);
        }
        if (l31 == 0) {
            float cb2v = cb2[0];
            #pragma unroll
            for (int r = 0; r < 16; ++r)
                s_wgt[m0 + (r & 3) + 8 * (r >> 2) + 4 * khalf] = part[r] + cb2v;
        }
    }
    __syncthreads();

    // ---- coord scatter (one thread/edge) ----
    if (tid < MT) {
        int e = tid;
        float wgt = s_wgt[e];
        int s = s_src[e], d = s_dst[e];
        float dx = coords[s * 3 + 0] - coords[d * 3 + 0];
        float dy = coords[s * 3 + 1] - coords[d * 3 + 1];
        float dz = coords[s * 3 + 2] - coords[d * 3 + 2];
        float inv = wgt / (sqrtf(dx * dx + dy * dy + dz * dz) + EPS);
        unsafeAtomicAdd(&out_coords[d * 3 + 0], dx * inv);
        unsafeAtomicAdd(&out_coords[d * 3 + 1], dy * inv);
        unsafeAtomicAdd(&out_coords[d * 3 + 2], dz * inv);
    }

    // ---- message scatter into node-output region (zeroed by prep) ----
#if __has_builtin(__builtin_amdgcn_global_atomic_fadd_v2f32)
    for (int idx = tid; idx < MT * D / 8; idx += 256) {
        int e = idx >> 4, c = idx & 15;
        bf16x8 m = *(const bf16x8*)&lds[MSG_OFF + e * HSTRIDE + c * 8];
        float* ap = &aggr_nodes[(size_t)s_dst[e] * D + c * 8];
        #pragma unroll
        for (int j = 0; j < 4; ++j) {
            f32x2 v; v[0] = bf2f(m[2 * j]); v[1] = bf2f(m[2 * j + 1]);
            __builtin_amdgcn_global_atomic_fadd_v2f32((f32x2*)(ap + 2 * j), v);
        }
    }
#else
    for (int idx = tid; idx < MT * D; idx += 256) {
        int e = idx >> 7, n = idx & 127;
        float v = bf2f(lds[MSG_OFF + e * HSTRIDE + n]);
        unsafeAtomicAdd(&aggr_nodes[(size_t)s_dst[e] * D + n], v);
    }
#endif
}

// ---------------------------------------------------------------------------
// node kernel (MFMA): 64 nodes/block. A = concat(nfbf, cvt(aggr));
// GEMM1 K=256 -> silu -> GEMM2 K=128 -> +bias +residual -> store fp32.
// nodes_io holds aggr on entry, final node output on exit (in place).
// ---------------------------------------------------------------------------
__global__ __launch_bounds__(256, 4)
void node_kernel(const float* __restrict__ node_feat,
                 const short* __restrict__ nfbf,
                 float* nodes_io,
                 const float* __restrict__ nb1, const float* __restrict__ nb2,
                 const short* __restrict__ wsf) {
    __shared__ __align__(16) short lds[MT * NSTRIDE];   // 33792 B
    const int tid = threadIdx.x;
    const int N0 = blockIdx.x * MT;

    {
        int i = tid >> 2, p = tid & 3;
        int nid = N0 + i; if (nid > N_NODES - 1) nid = N_NODES - 1;
        const short* frow = nfbf + (size_t)nid * D;
        short* drow = &lds[i * NSTRIDE];
        #pragma unroll
        for (int c = 0; c < 4; ++c)
            *(bf16x8*)&drow[c * 32 + p * 8] = *(const bf16x8*)&frow[c * 32 + p * 8];
        const float* arow = nodes_io + (size_t)nid * D + p * 32;
        #pragma unroll
        for (int c = 0; c < 4; ++c) {
            float4 f0 = *(const float4*)&arow[c * 8];
            float4 f1 = *(const float4*)&arow[c * 8 + 4];
            bf16x8 pk;
            pk[0]=f2bf(f0.x); pk[1]=f2bf(f0.y); pk[2]=f2bf(f0.z); pk[3]=f2bf(f0.w);
            pk[4]=f2bf(f1.x); pk[5]=f2bf(f1.y); pk[6]=f2bf(f1.z); pk[7]=f2bf(f1.w);
            *(bf16x8*)&drow[128 + p * 32 + c * 8] = pk;
        }
    }
    __syncthreads();

    const int lane  = tid & 63;
    const int wv    = tid >> 6;
    const int m0    = (wv >> 1) * 32;
    const int n0q   = wv & 1;
    const int l31   = lane & 31;
    const int khalf = lane >> 5;

    const bf16x8* W1 = (const bf16x8*)(wsf + NW1_OFF);
    const bf16x8* W2 = (const bf16x8*)(wsf + NW2_OFF);

    // ---- GEMM1: K=256 (16 kc) ----
    {
        f32x16 acc0, acc1;
        #pragma unroll
        for (int r = 0; r < 16; ++r) { acc0[r] = 0.f; acc1[r] = 0.f; }
        #pragma unroll
        for (int kc = 0; kc < 16; ++kc) {
            bf16x8 a  = *(const bf16x8*)&lds[(m0 + l31) * NSTRIDE + kc * 16 + khalf * 8];
            bf16x8 b0 = W1[(kc * 4 + n0q * 2 + 0) * 64 + lane];
            bf16x8 b1 = W1[(kc * 4 + n0q * 2 + 1) * 64 + lane];
            acc0 = __builtin_amdgcn_mfma_f32_32x32x16_bf16(a, b0, acc0, 0, 0, 0);
            acc1 = __builtin_amdgcn_mfma_f32_32x32x16_bf16(a, b1, acc1, 0, 0, 0);
        }
        __syncthreads();
        #pragma unroll
        for (int nt = 0; nt < 2; ++nt) {
            f32x16 A = nt ? acc1 : acc0;
            int n = n0q * 64 + nt * 32 + l31;
            float bb = nb1[n];
            #pragma unroll
            for (int r = 0; r < 16; ++r) {
                int row = (r & 3) + 8 * (r >> 2) + 4 * khalf;
                lds[(m0 + row) * HSTRIDE + n] = f2bf(silu_f(A[r] + bb));
            }
        }
    }
    __syncthreads();

    // ---- GEMM2: K=128 (8 kc); +bias +residual; store fp32 ----
    {
        f32x16 acc0, acc1;
        #pragma unroll
        for (int r = 0; r < 16; ++r) { acc0[r] = 0.f; acc1[r] = 0.f; }
        #pragma unroll
        for (int kc = 0; kc < 8; ++kc) {
            bf16x8 a  = *(const bf16x8*)&lds[(m0 + l31) * HSTRIDE + kc * 16 + khalf * 8];
            bf16x8 b0 = W2[(kc * 4 + n0q * 2 + 0) * 64 + lane];
            bf16x8 b1 = W2[(kc * 4 + n0q * 2 + 1) * 64 + lane];
            acc0 = __builtin_amdgcn_mfma_f32_32x32x16_bf16(a, b0, acc0, 0, 0, 0);
            acc1 = __builtin_amdgcn_mfma_f32_32x32x16_bf16(a, b1, acc1, 0, 0, 0);
        }
        #pragma unroll
        for (int nt = 0; nt < 2; ++nt) {
            f32x16 A = nt ? acc1 : acc0;
            int n = n0q * 64 + nt * 32 + l31;
            float bb = nb2[n];
            #pragma unroll
            for (int r = 0; r < 16; ++r) {
                int row = (r & 3) + 8 * (r >> 2) + 4 * khalf;
                int nid = N0 + m0 + row;
                if (nid < N_NODES)
                    nodes_io[(size_t)nid * D + n] = A[r] + bb + node_feat[(size_t)nid * D + n];
            }
        }
    }
}

extern "C" void kernel_launch(void* const* d_in, const int* in_sizes, int n_in,
                              void* d_out, int out_size, void* d_ws, size_t ws_size,
                              hipStream_t stream) {
    const float* node_feat  = (const float*)d_in[0];
    const int*   edge_index = (const int*)d_in[1];
    const float* edge_attr  = (const float*)d_in[2];
    const float* coords     = (const float*)d_in[3];
    const float* eW1 = (const float*)d_in[4];
    const float* eb1 = (const float*)d_in[5];
    const float* eW2 = (const float*)d_in[6];
    const float* eb2 = (const float*)d_in[7];
    const float* nW1 = (const float*)d_in[8];
    const float* nb1 = (const float*)d_in[9];
    const float* nW2 = (const float*)d_in[10];
    const float* nb2 = (const float*)d_in[11];
    const float* cW1 = (const float*)d_in[12];
    const float* cb1 = (const float*)d_in[13];
    const float* cW2 = (const float*)d_in[14];
    const float* cb2 = (const float*)d_in[15];

    float* nodes_io   = (float*)d_out;                 // aggr, then node output
    float* out_coords = nodes_io + (size_t)N_NODES * D;
    short* wsf  = (short*)d_ws;
    short* nfbf = wsf + NFBF_OFF;

    prep_kernel<<<256, 256, 0, stream>>>(
        eW1, eW2, cW1, nW1, nW2, node_feat, coords,
        wsf, nfbf, nodes_io, out_coords);
    edge_kernel<<<N_EDGES / MT, 256, 0, stream>>>(
        nfbf, edge_index, edge_attr, coords,
        eb1, eb2, cb1, cW2, cb2, wsf, nodes_io, out_coords);
    node_kernel<<<(N_NODES + MT - 1) / MT, 256, 0, stream>>>(
        node_feat, nfbf, nodes_io, nb1, nb2, wsf);
}

// Round 7
// 618.810 us; speedup vs baseline: 3.8004x; 1.0263x over previous
//
#include <hip/hip_runtime.h>
#include <math.h>

#define N_NODES 20000
#define N_EDGES 640000
#define D 128      // NODE_DIM == HID
#define ED 64      // EDGE_DIM
#define EPS 1e-8f
#define MT 64      // rows (edges/nodes) per block

#define FSTRIDE 328              // edge featA row stride (bf16): 320 + 8 pad
#define HSTRIDE 136              // h1/msg row stride: 128 + 8 pad
#define MSG_OFF (MT * HSTRIDE)   // msg region offset in shorts
#define LDS_SHORTS (MT * FSTRIDE)  // 20992 shorts = 41984 B

#define NSTRIDE 264              // node featA row stride: 256 + 8 pad

// d_ws layout (shorts unless noted):
//   eW1f @ 0 (80 frags) | eW2f @ 40960 | cW1f @ 57344 | nW1f @ 65536
//   nW2f @ 98304 | nfbf @ 114688 (2.56M shorts)
//   then i32: cnt @ short-ofs 2674688 (20000), cursor (+20000), perm (640000)
//   total 8,069,376 B  (ws_size proven >= 10.24 MB)
#define EW2_OFF 40960
#define CW1_OFF 57344
#define NW1_OFF 65536
#define NW2_OFF 98304
#define NFBF_OFF 114688
#define CSR_OFF  2674688   // in shorts; 4-byte aligned

typedef __attribute__((ext_vector_type(8))) short bf16x8;
typedef __attribute__((ext_vector_type(4))) short bf16x4;
typedef __attribute__((ext_vector_type(16))) float f32x16;

__device__ __forceinline__ float silu_f(float x) { return x / (1.0f + __expf(-x)); }

__device__ __forceinline__ short f2bf(float f) {   // RNE f32 -> bf16
    union { float f; unsigned u; } v; v.f = f;
    unsigned r = v.u + 0x7FFFu + ((v.u >> 16) & 1u);
    return (short)(r >> 16);
}
__device__ __forceinline__ float bf2f(short s) {
    union { unsigned u; float f; } v;
    v.u = ((unsigned)(unsigned short)s) << 16;
    return v.f;
}

#define SWZ_ADD(x, imm) (x + __int_as_float( \
    __builtin_amdgcn_ds_swizzle(__float_as_int(x), imm)))

// ---------------------------------------------------------------------------
// prep: weights -> 32x32x16 B-frag order; node_feat -> bf16; zero aggr; zero
// CSR counters; seed out_coords = coords.
// ---------------------------------------------------------------------------
__global__ __launch_bounds__(256)
void prep_kernel(const float* __restrict__ eW1, const float* __restrict__ eW2,
                 const float* __restrict__ cW1, const float* __restrict__ nW1,
                 const float* __restrict__ nW2,
                 const float* __restrict__ node_feat,
                 const float* __restrict__ coords,
                 short* __restrict__ wsf, short* __restrict__ nfbf,
                 int* __restrict__ cnt,
                 float* __restrict__ nodes_io, float* __restrict__ out_coords) {
    const int t = blockIdx.x * blockDim.x + threadIdx.x;
    const int nthr = gridDim.x * blockDim.x;

    if (t < 224 * 64) {
        int f = t >> 6, lane = t & 63;
        const float* src; int kc, nt, ncol; size_t dst;
        if (f < 80)       {              src = eW1; kc = f >> 2;  nt = f & 3;  ncol = 128; dst = (size_t)f * 512; }
        else if (f < 112) { int g=f-80;  src = eW2; kc = g >> 2;  nt = g & 3;  ncol = 128; dst = EW2_OFF + (size_t)g * 512; }
        else if (f < 128) { int g=f-112; src = cW1; kc = g >> 1;  nt = g & 1;  ncol = 64;  dst = CW1_OFF + (size_t)g * 512; }
        else if (f < 192) { int g=f-128; src = nW1; kc = g >> 2;  nt = g & 3;  ncol = 128; dst = NW1_OFF + (size_t)g * 512; }
        else              { int g=f-192; src = nW2; kc = g >> 2;  nt = g & 3;  ncol = 128; dst = NW2_OFF + (size_t)g * 512; }
        int col = nt * 32 + (lane & 31);
        int k0  = kc * 16 + (lane >> 5) * 8;
        bf16x8 o;
        #pragma unroll
        for (int j = 0; j < 8; ++j) o[j] = f2bf(src[(size_t)(k0 + j) * ncol + col]);
        *(bf16x8*)&wsf[dst + (size_t)lane * 8] = o;
    }
    for (int idx = t; idx < N_NODES * D / 8; idx += nthr) {
        const float* s = node_feat + (size_t)idx * 8;
        float4 f0 = *(const float4*)s, f1 = *(const float4*)(s + 4);
        bf16x8 pk;
        pk[0]=f2bf(f0.x); pk[1]=f2bf(f0.y); pk[2]=f2bf(f0.z); pk[3]=f2bf(f0.w);
        pk[4]=f2bf(f1.x); pk[5]=f2bf(f1.y); pk[6]=f2bf(f1.z); pk[7]=f2bf(f1.w);
        *(bf16x8*)&nfbf[(size_t)idx * 8] = pk;
    }
    for (int idx = t; idx < N_NODES * D / 4; idx += nthr) {
        float4 z; z.x = 0.f; z.y = 0.f; z.z = 0.f; z.w = 0.f;
        *(float4*)&nodes_io[(size_t)idx * 4] = z;
    }
    for (int idx = t; idx < N_NODES; idx += nthr) cnt[idx] = 0;
    for (int idx = t; idx < N_NODES * 3; idx += nthr)
        out_coords[idx] = coords[idx];
}

// ---------------------------------------------------------------------------
// CSR build: histogram -> exclusive scan -> scatter (contiguous per-dst runs;
// intra-run order arbitrary, sums don't care).
// ---------------------------------------------------------------------------
__global__ __launch_bounds__(256)
void hist_kernel(const int* __restrict__ edge_index, int* __restrict__ cnt) {
    int t = blockIdx.x * blockDim.x + threadIdx.x;
    if (t < N_EDGES) atomicAdd(&cnt[edge_index[N_EDGES + t]], 1);
}

#define SCAN_T 1024
#define SCAN_C 20
__global__ __launch_bounds__(SCAN_T)
void scan_kernel(const int* __restrict__ cnt, int* __restrict__ cursor) {
    __shared__ int part[SCAN_T];
    const int t = threadIdx.x;
    const int base = t * SCAN_C;
    int s = 0;
    #pragma unroll
    for (int i = 0; i < SCAN_C; ++i) {
        int idx = base + i;
        if (idx < N_NODES) s += cnt[idx];
    }
    part[t] = s;
    __syncthreads();
    for (int off = 1; off < SCAN_T; off <<= 1) {
        int v = (t >= off) ? part[t - off] : 0;
        __syncthreads();
        part[t] += v;
        __syncthreads();
    }
    int run = part[t] - s;   // exclusive prefix of this thread's chunk
    #pragma unroll
    for (int i = 0; i < SCAN_C; ++i) {
        int idx = base + i;
        if (idx < N_NODES) { cursor[idx] = run; run += cnt[idx]; }
    }
}

__global__ __launch_bounds__(256)
void scatter_kernel(const int* __restrict__ edge_index,
                    int* __restrict__ cursor, int* __restrict__ perm) {
    int t = blockIdx.x * blockDim.x + threadIdx.x;
    if (t < N_EDGES) {
        int d = edge_index[N_EDGES + t];
        int pos = atomicAdd(&cursor[d], 1);
        perm[pos] = t;
    }
}

// ---------------------------------------------------------------------------
// edge kernel: processes 64 dst-sorted edges (via perm). MFMA edge-MLP +
// coord-MLP; aggregation = in-LDS segment reduction, one scalar-atomic
// flush group per (segment x column-quad x row-stripe).
// ---------------------------------------------------------------------------
__global__ __launch_bounds__(256, 3)
void edge_kernel(const short* __restrict__ nfbf,
                 const int* __restrict__ edge_index,
                 const int* __restrict__ perm,
                 const float* __restrict__ edge_attr,
                 const float* __restrict__ coords,
                 const float* __restrict__ eb1, const float* __restrict__ eb2,
                 const float* __restrict__ cb1, const float* __restrict__ cW2,
                 const float* __restrict__ cb2,
                 const short* __restrict__ wsf,
                 float* __restrict__ aggr_nodes, float* __restrict__ out_coords) {
    __shared__ __align__(16) short lds[LDS_SHORTS];
    __shared__ int s_src[MT], s_dst[MT];
    __shared__ float s_wgt[MT];
    __shared__ float s_cv[MT][3];
    __shared__ char s_segend[MT];

    const int tid = threadIdx.x;
    const int E0 = blockIdx.x * MT;

    // ---- stage A1 rows in perm order ----
    {
        int i = tid >> 2, p = tid & 3;           // 4 threads/edge
        int eid  = perm[E0 + i];
        int esrc = edge_index[eid];
        int edst = edge_index[N_EDGES + eid];
        if (p == 0) { s_src[i] = esrc; s_dst[i] = edst; }
        const short* srow = nfbf + (size_t)esrc * D;
        const short* drow = nfbf + (size_t)edst * D;
        short* frow = &lds[i * FSTRIDE];
        #pragma unroll
        for (int c = 0; c < 4; ++c)
            *(bf16x8*)&frow[c * 32 + p * 8] = *(const bf16x8*)&srow[c * 32 + p * 8];
        #pragma unroll
        for (int c = 0; c < 4; ++c)
            *(bf16x8*)&frow[128 + c * 32 + p * 8] = *(const bf16x8*)&drow[c * 32 + p * 8];
        const float* arow = edge_attr + (size_t)eid * ED + p * 16;
        float4 a0 = *(const float4*)&arow[0], a1 = *(const float4*)&arow[4];
        float4 a2 = *(const float4*)&arow[8], a3 = *(const float4*)&arow[12];
        bf16x8 p0, p1;
        p0[0]=f2bf(a0.x); p0[1]=f2bf(a0.y); p0[2]=f2bf(a0.z); p0[3]=f2bf(a0.w);
        p0[4]=f2bf(a1.x); p0[5]=f2bf(a1.y); p0[6]=f2bf(a1.z); p0[7]=f2bf(a1.w);
        p1[0]=f2bf(a2.x); p1[1]=f2bf(a2.y); p1[2]=f2bf(a2.z); p1[3]=f2bf(a2.w);
        p1[4]=f2bf(a3.x); p1[5]=f2bf(a3.y); p1[6]=f2bf(a3.z); p1[7]=f2bf(a3.w);
        *(bf16x8*)&frow[256 + p * 16]     = p0;
        *(bf16x8*)&frow[256 + p * 16 + 8] = p1;
    }
    __syncthreads();

    // segment-end flags (dst sorted within block)
    if (tid < MT)
        s_segend[tid] = (tid == MT - 1) || (s_dst[tid] != s_dst[tid + 1]);

    const int lane  = tid & 63;
    const int wv    = tid >> 6;
    const int m0    = (wv >> 1) * 32;
    const int n0q   = wv & 1;
    const int l31   = lane & 31;
    const int khalf = lane >> 5;

    const bf16x8* W1 = (const bf16x8*)wsf;
    const bf16x8* W2 = (const bf16x8*)(wsf + EW2_OFF);
    const bf16x8* W3 = (const bf16x8*)(wsf + CW1_OFF);

    // ---- GEMM1: h1 = silu(feat @ eW1 + eb1), K=320 (20 kc) ----
    {
        f32x16 acc0, acc1;
        #pragma unroll
        for (int r = 0; r < 16; ++r) { acc0[r] = 0.f; acc1[r] = 0.f; }
        #pragma unroll
        for (int kc = 0; kc < 20; ++kc) {
            bf16x8 a  = *(const bf16x8*)&lds[(m0 + l31) * FSTRIDE + kc * 16 + khalf * 8];
            bf16x8 b0 = W1[(kc * 4 + n0q * 2 + 0) * 64 + lane];
            bf16x8 b1 = W1[(kc * 4 + n0q * 2 + 1) * 64 + lane];
            acc0 = __builtin_amdgcn_mfma_f32_32x32x16_bf16(a, b0, acc0, 0, 0, 0);
            acc1 = __builtin_amdgcn_mfma_f32_32x32x16_bf16(a, b1, acc1, 0, 0, 0);
        }
        __syncthreads();   // all waves done reading feat; overlay h1
        #pragma unroll
        for (int nt = 0; nt < 2; ++nt) {
            f32x16 A = nt ? acc1 : acc0;
            int n = n0q * 64 + nt * 32 + l31;
            float bb = eb1[n];
            #pragma unroll
            for (int r = 0; r < 16; ++r) {
                int row = (r & 3) + 8 * (r >> 2) + 4 * khalf;
                lds[(m0 + row) * HSTRIDE + n] = f2bf(silu_f(A[r] + bb));
            }
        }
    }
    __syncthreads();

    // ---- GEMM2: msg = silu(h1 @ eW2 + eb2), K=128 (8 kc) ----
    {
        f32x16 acc0, acc1;
        #pragma unroll
        for (int r = 0; r < 16; ++r) { acc0[r] = 0.f; acc1[r] = 0.f; }
        #pragma unroll
        for (int kc = 0; kc < 8; ++kc) {
            bf16x8 a  = *(const bf16x8*)&lds[(m0 + l31) * HSTRIDE + kc * 16 + khalf * 8];
            bf16x8 b0 = W2[(kc * 4 + n0q * 2 + 0) * 64 + lane];
            bf16x8 b1 = W2[(kc * 4 + n0q * 2 + 1) * 64 + lane];
            acc0 = __builtin_amdgcn_mfma_f32_32x32x16_bf16(a, b0, acc0, 0, 0, 0);
            acc1 = __builtin_amdgcn_mfma_f32_32x32x16_bf16(a, b1, acc1, 0, 0, 0);
        }
        #pragma unroll
        for (int nt = 0; nt < 2; ++nt) {
            f32x16 A = nt ? acc1 : acc0;
            int n = n0q * 64 + nt * 32 + l31;
            float bb = eb2[n];
            #pragma unroll
            for (int r = 0; r < 16; ++r) {
                int row = (r & 3) + 8 * (r >> 2) + 4 * khalf;
                lds[MSG_OFF + (m0 + row) * HSTRIDE + n] = f2bf(silu_f(A[r] + bb));
            }
        }
    }
    __syncthreads();

    // ---- GEMM3: h3 = silu(msg @ cW1 + cb1); per-edge w = h3 @ cW2 + cb2 ----
    {
        f32x16 c0, c1;
        #pragma unroll
        for (int r = 0; r < 16; ++r) { c0[r] = 0.f; c1[r] = 0.f; }
        #pragma unroll
        for (int kc = 0; kc < 8; ++kc) {
            bf16x8 a  = *(const bf16x8*)&lds[MSG_OFF + (m0 + l31) * HSTRIDE + kc * 16 + khalf * 8];
            bf16x8 b0 = W3[(kc * 2 + 0) * 64 + lane];
            bf16x8 b1 = W3[(kc * 2 + 1) * 64 + lane];
            c0 = __builtin_amdgcn_mfma_f32_32x32x16_bf16(a, b0, c0, 0, 0, 0);
            c1 = __builtin_amdgcn_mfma_f32_32x32x16_bf16(a, b1, c1, 0, 0, 0);
        }
        float b1a = cb1[l31], b1b = cb1[32 + l31];
        float w2a = cW2[l31], w2b = cW2[32 + l31];
        float part[16];
        #pragma unroll
        for (int r = 0; r < 16; ++r)
            part[r] = silu_f(c0[r] + b1a) * w2a + silu_f(c1[r] + b1b) * w2b;
        #pragma unroll
        for (int r = 0; r < 16; ++r) {
            part[r] = SWZ_ADD(part[r], 0x041F);
            part[r] = SWZ_ADD(part[r], 0x081F);
            part[r] = SWZ_ADD(part[r], 0x101F);
            part[r] = SWZ_ADD(part[r], 0x201F);
            part[r] = SWZ_ADD(part[r], 0x401F);
        }
        if (l31 == 0) {
            float cb2v = cb2[0];
            #pragma unroll
            for (int r = 0; r < 16; ++r)
                s_wgt[m0 + (r & 3) + 8 * (r >> 2) + 4 * khalf] = part[r] + cb2v;
        }
    }
    __syncthreads();

    // ---- per-edge coord vector into LDS ----
    if (tid < MT) {
        int e = tid;
        float wgt = s_wgt[e];
        int s = s_src[e], d = s_dst[e];
        float dx = coords[s * 3 + 0] - coords[d * 3 + 0];
        float dy = coords[s * 3 + 1] - coords[d * 3 + 1];
        float dz = coords[s * 3 + 2] - coords[d * 3 + 2];
        float inv = wgt / (sqrtf(dx * dx + dy * dy + dz * dz) + EPS);
        s_cv[e][0] = dx * inv; s_cv[e][1] = dy * inv; s_cv[e][2] = dz * inv;
    }
    __syncthreads();

    // ---- message segment-reduction: thread = (column quad, row stripe) ----
    {
        int q  = tid & 31;        // cols q*4 .. q*4+3
        int st = tid >> 5;        // rows st*8 .. st*8+7
        int c0 = q * 4;
        float a0 = 0.f, a1 = 0.f, a2 = 0.f, a3 = 0.f;
        #pragma unroll
        for (int r = 0; r < 8; ++r) {
            int e = st * 8 + r;
            bf16x4 m = *(const bf16x4*)&lds[MSG_OFF + e * HSTRIDE + c0];
            a0 += bf2f(m[0]); a1 += bf2f(m[1]); a2 += bf2f(m[2]); a3 += bf2f(m[3]);
            if (s_segend[e]) {
                float* ap = &aggr_nodes[(size_t)s_dst[e] * D + c0];
                unsafeAtomicAdd(ap + 0, a0); unsafeAtomicAdd(ap + 1, a1);
                unsafeAtomicAdd(ap + 2, a2); unsafeAtomicAdd(ap + 3, a3);
                a0 = a1 = a2 = a3 = 0.f;
            }
        }
        int elast = st * 8 + 7;
        if (!s_segend[elast]) {
            float* ap = &aggr_nodes[(size_t)s_dst[elast] * D + c0];
            unsafeAtomicAdd(ap + 0, a0); unsafeAtomicAdd(ap + 1, a1);
            unsafeAtomicAdd(ap + 2, a2); unsafeAtomicAdd(ap + 3, a3);
        }
    }

    // ---- coord segment-reduction: segment heads walk their run ----
    if (tid < MT) {
        int e = tid;
        bool head = (e == 0) || (s_dst[e] != s_dst[e - 1]);
        if (head) {
            float sx = 0.f, sy = 0.f, sz = 0.f;
            int j = e;
            do {
                sx += s_cv[j][0]; sy += s_cv[j][1]; sz += s_cv[j][2];
                ++j;
            } while (j < MT && s_dst[j] == s_dst[e]);
            int d = s_dst[e];
            unsafeAtomicAdd(&out_coords[d * 3 + 0], sx);
            unsafeAtomicAdd(&out_coords[d * 3 + 1], sy);
            unsafeAtomicAdd(&out_coords[d * 3 + 2], sz);
        }
    }
}

// ---------------------------------------------------------------------------
// node kernel (MFMA): 64 nodes/block; in-place aggr -> output.
// ---------------------------------------------------------------------------
__global__ __launch_bounds__(256, 4)
void node_kernel(const float* __restrict__ node_feat,
                 const short* __restrict__ nfbf,
                 float* nodes_io,
                 const float* __restrict__ nb1, const float* __restrict__ nb2,
                 const short* __restrict__ wsf) {
    __shared__ __align__(16) short lds[MT * NSTRIDE];
    const int tid = threadIdx.x;
    const int N0 = blockIdx.x * MT;

    {
        int i = tid >> 2, p = tid & 3;
        int nid = N0 + i; if (nid > N_NODES - 1) nid = N_NODES - 1;
        const short* frow = nfbf + (size_t)nid * D;
        short* drow = &lds[i * NSTRIDE];
        #pragma unroll
        for (int c = 0; c < 4; ++c)
            *(bf16x8*)&drow[c * 32 + p * 8] = *(const bf16x8*)&frow[c * 32 + p * 8];
        const float* arow = nodes_io + (size_t)nid * D + p * 32;
        #pragma unroll
        for (int c = 0; c < 4; ++c) {
            float4 f0 = *(const float4*)&arow[c * 8];
            float4 f1 = *(const float4*)&arow[c * 8 + 4];
            bf16x8 pk;
            pk[0]=f2bf(f0.x); pk[1]=f2bf(f0.y); pk[2]=f2bf(f0.z); pk[3]=f2bf(f0.w);
            pk[4]=f2bf(f1.x); pk[5]=f2bf(f1.y); pk[6]=f2bf(f1.z); pk[7]=f2bf(f1.w);
            *(bf16x8*)&drow[128 + p * 32 + c * 8] = pk;
        }
    }
    __syncthreads();

    const int lane  = tid & 63;
    const int wv    = tid >> 6;
    const int m0    = (wv >> 1) * 32;
    const int n0q   = wv & 1;
    const int l31   = lane & 31;
    const int khalf = lane >> 5;

    const bf16x8* W1 = (const bf16x8*)(wsf + NW1_OFF);
    const bf16x8* W2 = (const bf16x8*)(wsf + NW2_OFF);

    {
        f32x16 acc0, acc1;
        #pragma unroll
        for (int r = 0; r < 16; ++r) { acc0[r] = 0.f; acc1[r] = 0.f; }
        #pragma unroll
        for (int kc = 0; kc < 16; ++kc) {
            bf16x8 a  = *(const bf16x8*)&lds[(m0 + l31) * NSTRIDE + kc * 16 + khalf * 8];
            bf16x8 b0 = W1[(kc * 4 + n0q * 2 + 0) * 64 + lane];
            bf16x8 b1 = W1[(kc * 4 + n0q * 2 + 1) * 64 + lane];
            acc0 = __builtin_amdgcn_mfma_f32_32x32x16_bf16(a, b0, acc0, 0, 0, 0);
            acc1 = __builtin_amdgcn_mfma_f32_32x32x16_bf16(a, b1, acc1, 0, 0, 0);
        }
        __syncthreads();
        #pragma unroll
        for (int nt = 0; nt < 2; ++nt) {
            f32x16 A = nt ? acc1 : acc0;
            int n = n0q * 64 + nt * 32 + l31;
            float bb = nb1[n];
            #pragma unroll
            for (int r = 0; r < 16; ++r) {
                int row = (r & 3) + 8 * (r >> 2) + 4 * khalf;
                lds[(m0 + row) * HSTRIDE + n] = f2bf(silu_f(A[r] + bb));
            }
        }
    }
    __syncthreads();

    {
        f32x16 acc0, acc1;
        #pragma unroll
        for (int r = 0; r < 16; ++r) { acc0[r] = 0.f; acc1[r] = 0.f; }
        #pragma unroll
        for (int kc = 0; kc < 8; ++kc) {
            bf16x8 a  = *(const bf16x8*)&lds[(m0 + l31) * HSTRIDE + kc * 16 + khalf * 8];
            bf16x8 b0 = W2[(kc * 4 + n0q * 2 + 0) * 64 + lane];
            bf16x8 b1 = W2[(kc * 4 + n0q * 2 + 1) * 64 + lane];
            acc0 = __builtin_amdgcn_mfma_f32_32x32x16_bf16(a, b0, acc0, 0, 0, 0);
            acc1 = __builtin_amdgcn_mfma_f32_32x32x16_bf16(a, b1, acc1, 0, 0, 0);
        }
        #pragma unroll
        for (int nt = 0; nt < 2; ++nt) {
            f32x16 A = nt ? acc1 : acc0;
            int n = n0q * 64 + nt * 32 + l31;
            float bb = nb2[n];
            #pragma unroll
            for (int r = 0; r < 16; ++r) {
                int row = (r & 3) + 8 * (r >> 2) + 4 * khalf;
                int nid = N0 + m0 + row;
                if (nid < N_NODES)
                    nodes_io[(size_t)nid * D + n] = A[r] + bb + node_feat[(size_t)nid * D + n];
            }
        }
    }
}

extern "C" void kernel_launch(void* const* d_in, const int* in_sizes, int n_in,
                              void* d_out, int out_size, void* d_ws, size_t ws_size,
                              hipStream_t stream) {
    const float* node_feat  = (const float*)d_in[0];
    const int*   edge_index = (const int*)d_in[1];
    const float* edge_attr  = (const float*)d_in[2];
    const float* coords     = (const float*)d_in[3];
    const float* eW1 = (const float*)d_in[4];
    const float* eb1 = (const float*)d_in[5];
    const float* eW2 = (const float*)d_in[6];
    const float* eb2 = (const float*)d_in[7];
    const float* nW1 = (const float*)d_in[8];
    const float* nb1 = (const float*)d_in[9];
    const float* nW2 = (const float*)d_in[10];
    const float* nb2 = (const float*)d_in[11];
    const float* cW1 = (const float*)d_in[12];
    const float* cb1 = (const float*)d_in[13];
    const float* cW2 = (const float*)d_in[14];
    const float* cb2 = (const float*)d_in[15];

    float* nodes_io   = (float*)d_out;                 // aggr, then node output
    float* out_coords = nodes_io + (size_t)N_NODES * D;
    short* wsf    = (short*)d_ws;
    short* nfbf   = wsf + NFBF_OFF;
    int*   cnt    = (int*)(wsf + CSR_OFF);
    int*   cursor = cnt + N_NODES;
    int*   perm   = cursor + N_NODES;

    prep_kernel<<<256, 256, 0, stream>>>(
        eW1, eW2, cW1, nW1, nW2, node_feat, coords,
        wsf, nfbf, cnt, nodes_io, out_coords);
    hist_kernel<<<N_EDGES / 256, 256, 0, stream>>>(edge_index, cnt);
    scan_kernel<<<1, SCAN_T, 0, stream>>>(cnt, cursor);
    scatter_kernel<<<N_EDGES / 256, 256, 0, stream>>>(edge_index, cursor, perm);
    edge_kernel<<<N_EDGES / MT, 256, 0, stream>>>(
        nfbf, edge_index, perm, edge_attr, coords,
        eb1, eb2, cb1, cW2, cb2, wsf, nodes_io, out_coords);
    node_kernel<<<(N_NODES + MT - 1) / MT, 256, 0, stream>>>(
        node_feat, nfbf, nodes_io, nb1, nb2, wsf);
}

// Round 8
// 609.224 us; speedup vs baseline: 3.8602x; 1.0157x over previous
//
#include <hip/hip_runtime.h>
#include <math.h>

#define N_NODES 20000
#define N_EDGES 640000
#define D 128      // NODE_DIM == HID
#define ED 64      // EDGE_DIM
#define EPS 1e-8f
#define MT 64      // rows (edges/nodes) per block

#define RSTRIDE 136              // shared region row stride (bf16): 128 + 8 pad
#define HSTRIDE 136              // node kernel h1 stride
#define NSTRIDE 264              // node featA row stride: 256 + 8 pad

// d_ws layout (shorts unless noted):
//   eW1f @ 0 (80 frags) | eW2f @ 40960 | cW1f @ 57344 | nW1f @ 65536
//   nW2f @ 98304 | nfbf @ 114688 (2.56M shorts)
//   then i32: cnt @ short-ofs 2674688 (20000), cursor (+20000), perm (640000)
//   total 8,069,376 B  (ws_size proven >= 10.24 MB)
#define EW2_OFF 40960
#define CW1_OFF 57344
#define NW1_OFF 65536
#define NW2_OFF 98304
#define NFBF_OFF 114688
#define CSR_OFF  2674688   // in shorts; 4-byte aligned

typedef __attribute__((ext_vector_type(8))) short bf16x8;
typedef __attribute__((ext_vector_type(4))) short bf16x4;
typedef __attribute__((ext_vector_type(16))) float f32x16;

__device__ __forceinline__ float silu_f(float x) { return x / (1.0f + __expf(-x)); }

__device__ __forceinline__ short f2bf(float f) {   // RNE f32 -> bf16
    union { float f; unsigned u; } v; v.f = f;
    unsigned r = v.u + 0x7FFFu + ((v.u >> 16) & 1u);
    return (short)(r >> 16);
}
__device__ __forceinline__ float bf2f(short s) {
    union { unsigned u; float f; } v;
    v.u = ((unsigned)(unsigned short)s) << 16;
    return v.f;
}

#define SWZ_ADD(x, imm) (x + __int_as_float( \
    __builtin_amdgcn_ds_swizzle(__float_as_int(x), imm)))

// ---------------------------------------------------------------------------
// prep: weights -> 32x32x16 B-frag order; node_feat -> bf16; zero aggr; zero
// CSR counters; seed out_coords = coords.
// ---------------------------------------------------------------------------
__global__ __launch_bounds__(256)
void prep_kernel(const float* __restrict__ eW1, const float* __restrict__ eW2,
                 const float* __restrict__ cW1, const float* __restrict__ nW1,
                 const float* __restrict__ nW2,
                 const float* __restrict__ node_feat,
                 const float* __restrict__ coords,
                 short* __restrict__ wsf, short* __restrict__ nfbf,
                 int* __restrict__ cnt,
                 float* __restrict__ nodes_io, float* __restrict__ out_coords) {
    const int t = blockIdx.x * blockDim.x + threadIdx.x;
    const int nthr = gridDim.x * blockDim.x;

    if (t < 224 * 64) {
        int f = t >> 6, lane = t & 63;
        const float* src; int kc, nt, ncol; size_t dst;
        if (f < 80)       {              src = eW1; kc = f >> 2;  nt = f & 3;  ncol = 128; dst = (size_t)f * 512; }
        else if (f < 112) { int g=f-80;  src = eW2; kc = g >> 2;  nt = g & 3;  ncol = 128; dst = EW2_OFF + (size_t)g * 512; }
        else if (f < 128) { int g=f-112; src = cW1; kc = g >> 1;  nt = g & 1;  ncol = 64;  dst = CW1_OFF + (size_t)g * 512; }
        else if (f < 192) { int g=f-128; src = nW1; kc = g >> 2;  nt = g & 3;  ncol = 128; dst = NW1_OFF + (size_t)g * 512; }
        else              { int g=f-192; src = nW2; kc = g >> 2;  nt = g & 3;  ncol = 128; dst = NW2_OFF + (size_t)g * 512; }
        int col = nt * 32 + (lane & 31);
        int k0  = kc * 16 + (lane >> 5) * 8;
        bf16x8 o;
        #pragma unroll
        for (int j = 0; j < 8; ++j) o[j] = f2bf(src[(size_t)(k0 + j) * ncol + col]);
        *(bf16x8*)&wsf[dst + (size_t)lane * 8] = o;
    }
    for (int idx = t; idx < N_NODES * D / 8; idx += nthr) {
        const float* s = node_feat + (size_t)idx * 8;
        float4 f0 = *(const float4*)s, f1 = *(const float4*)(s + 4);
        bf16x8 pk;
        pk[0]=f2bf(f0.x); pk[1]=f2bf(f0.y); pk[2]=f2bf(f0.z); pk[3]=f2bf(f0.w);
        pk[4]=f2bf(f1.x); pk[5]=f2bf(f1.y); pk[6]=f2bf(f1.z); pk[7]=f2bf(f1.w);
        *(bf16x8*)&nfbf[(size_t)idx * 8] = pk;
    }
    for (int idx = t; idx < N_NODES * D / 4; idx += nthr) {
        float4 z; z.x = 0.f; z.y = 0.f; z.z = 0.f; z.w = 0.f;
        *(float4*)&nodes_io[(size_t)idx * 4] = z;
    }
    for (int idx = t; idx < N_NODES; idx += nthr) cnt[idx] = 0;
    for (int idx = t; idx < N_NODES * 3; idx += nthr)
        out_coords[idx] = coords[idx];
}

// ---------------------------------------------------------------------------
// CSR build: histogram -> exclusive scan (LDS-staged, coalesced) -> scatter.
// ---------------------------------------------------------------------------
__global__ __launch_bounds__(256)
void hist_kernel(const int* __restrict__ edge_index, int* __restrict__ cnt) {
    int t = blockIdx.x * blockDim.x + threadIdx.x;
    if (t < N_EDGES) atomicAdd(&cnt[edge_index[N_EDGES + t]], 1);
}

#define SCAN_T 1024
#define SCAN_C 20
__global__ __launch_bounds__(SCAN_T)
void scan_kernel(const int* __restrict__ cnt, int* __restrict__ cursor) {
    __shared__ int lc[N_NODES];      // 80 KB, single block
    __shared__ int part[SCAN_T];
    const int t = threadIdx.x;
    for (int i = t * 4; i < N_NODES; i += SCAN_T * 4)
        *(int4*)&lc[i] = *(const int4*)&cnt[i];
    __syncthreads();
    const int base = t * SCAN_C;
    int s = 0;
    #pragma unroll
    for (int i = 0; i < SCAN_C; ++i) {
        int idx = base + i;
        if (idx < N_NODES) s += lc[idx];
    }
    part[t] = s;
    __syncthreads();
    for (int off = 1; off < SCAN_T; off <<= 1) {
        int v = (t >= off) ? part[t - off] : 0;
        __syncthreads();
        part[t] += v;
        __syncthreads();
    }
    int run = part[t] - s;   // exclusive prefix of this thread's chunk
    #pragma unroll
    for (int i = 0; i < SCAN_C; ++i) {
        int idx = base + i;
        if (idx < N_NODES) { int c = lc[idx]; lc[idx] = run; run += c; }
    }
    __syncthreads();
    for (int i = t * 4; i < N_NODES; i += SCAN_T * 4)
        *(int4*)&cursor[i] = *(const int4*)&lc[i];
}

__global__ __launch_bounds__(256)
void scatter_kernel(const int* __restrict__ edge_index,
                    int* __restrict__ cursor, int* __restrict__ perm) {
    int t = blockIdx.x * blockDim.x + threadIdx.x;
    if (t < N_EDGES) {
        int d = edge_index[N_EDGES + t];
        int pos = atomicAdd(&cursor[d], 1);
        perm[pos] = t;
    }
}

// ---------------------------------------------------------------------------
// edge kernel: 64 dst-sorted edges/block. GEMM1's 320-wide A is staged in 3
// chunks (src 128 / dst 128 / ea 64) through ONE 17.4 KB LDS region that is
// later reused for h1 and msg (disjoint live ranges, barriers between).
// LDS ~19.5 KB -> 24 waves/CU with __launch_bounds__(256,6).
// ---------------------------------------------------------------------------
__global__ __launch_bounds__(256, 6)
void edge_kernel(const short* __restrict__ nfbf,
                 const int* __restrict__ edge_index,
                 const int* __restrict__ perm,
                 const float* __restrict__ edge_attr,
                 const float* __restrict__ coords,
                 const float* __restrict__ eb1, const float* __restrict__ eb2,
                 const float* __restrict__ cb1, const float* __restrict__ cW2,
                 const float* __restrict__ cb2,
                 const short* __restrict__ wsf,
                 float* __restrict__ aggr_nodes, float* __restrict__ out_coords) {
    __shared__ __align__(16) short R[MT * RSTRIDE];   // 8704 shorts = 17408 B
    __shared__ int s_src[MT], s_dst[MT];
    __shared__ float s_wgt[MT];
    __shared__ float s_cv[MT][3];
    __shared__ char s_segend[MT];

    const int tid = threadIdx.x;
    const int E0 = blockIdx.x * MT;

    const int ie = tid >> 2, p = tid & 3;       // 4 threads/edge
    const int eid  = perm[E0 + ie];
    const int esrc = edge_index[eid];
    const int edst = edge_index[N_EDGES + eid];
    if (p == 0) { s_src[ie] = esrc; s_dst[ie] = edst; }

    // ---- stage chunk 0: src rows ----
    {
        const short* row = nfbf + (size_t)esrc * D;
        #pragma unroll
        for (int c = 0; c < 4; ++c)
            *(bf16x8*)&R[ie * RSTRIDE + c * 32 + p * 8] = *(const bf16x8*)&row[c * 32 + p * 8];
    }
    __syncthreads();                                           // B1
    if (tid < MT)
        s_segend[tid] = (tid == MT - 1) || (s_dst[tid] != s_dst[tid + 1]);

    const int lane  = tid & 63;
    const int wv    = tid >> 6;
    const int m0    = (wv >> 1) * 32;
    const int n0q   = wv & 1;
    const int l31   = lane & 31;
    const int khalf = lane >> 5;

    const bf16x8* W1 = (const bf16x8*)wsf;
    const bf16x8* W2 = (const bf16x8*)(wsf + EW2_OFF);
    const bf16x8* W3 = (const bf16x8*)(wsf + CW1_OFF);

    f32x16 acc0, acc1;
    #pragma unroll
    for (int r = 0; r < 16; ++r) { acc0[r] = 0.f; acc1[r] = 0.f; }

    // ---- GEMM1a: kc 0..7 (src cols) ----
    #pragma unroll
    for (int kcl = 0; kcl < 8; ++kcl) {
        bf16x8 a  = *(const bf16x8*)&R[(m0 + l31) * RSTRIDE + kcl * 16 + khalf * 8];
        bf16x8 b0 = W1[((kcl) * 4 + n0q * 2 + 0) * 64 + lane];
        bf16x8 b1 = W1[((kcl) * 4 + n0q * 2 + 1) * 64 + lane];
        acc0 = __builtin_amdgcn_mfma_f32_32x32x16_bf16(a, b0, acc0, 0, 0, 0);
        acc1 = __builtin_amdgcn_mfma_f32_32x32x16_bf16(a, b1, acc1, 0, 0, 0);
    }
    __syncthreads();                                           // B2

    // ---- stage chunk 1: dst rows ----
    {
        const short* row = nfbf + (size_t)edst * D;
        #pragma unroll
        for (int c = 0; c < 4; ++c)
            *(bf16x8*)&R[ie * RSTRIDE + c * 32 + p * 8] = *(const bf16x8*)&row[c * 32 + p * 8];
    }
    __syncthreads();                                           // B3

    // ---- GEMM1b: kc 8..15 (dst cols) ----
    #pragma unroll
    for (int kcl = 0; kcl < 8; ++kcl) {
        bf16x8 a  = *(const bf16x8*)&R[(m0 + l31) * RSTRIDE + kcl * 16 + khalf * 8];
        bf16x8 b0 = W1[((8 + kcl) * 4 + n0q * 2 + 0) * 64 + lane];
        bf16x8 b1 = W1[((8 + kcl) * 4 + n0q * 2 + 1) * 64 + lane];
        acc0 = __builtin_amdgcn_mfma_f32_32x32x16_bf16(a, b0, acc0, 0, 0, 0);
        acc1 = __builtin_amdgcn_mfma_f32_32x32x16_bf16(a, b1, acc1, 0, 0, 0);
    }
    __syncthreads();                                           // B4

    // ---- stage chunk 2: edge_attr (64 cols, f32->bf16) ----
    {
        const float* arow = edge_attr + (size_t)eid * ED + p * 16;
        float4 a0 = *(const float4*)&arow[0], a1 = *(const float4*)&arow[4];
        float4 a2 = *(const float4*)&arow[8], a3 = *(const float4*)&arow[12];
        bf16x8 p0, p1;
        p0[0]=f2bf(a0.x); p0[1]=f2bf(a0.y); p0[2]=f2bf(a0.z); p0[3]=f2bf(a0.w);
        p0[4]=f2bf(a1.x); p0[5]=f2bf(a1.y); p0[6]=f2bf(a1.z); p0[7]=f2bf(a1.w);
        p1[0]=f2bf(a2.x); p1[1]=f2bf(a2.y); p1[2]=f2bf(a2.z); p1[3]=f2bf(a2.w);
        p1[4]=f2bf(a3.x); p1[5]=f2bf(a3.y); p1[6]=f2bf(a3.z); p1[7]=f2bf(a3.w);
        *(bf16x8*)&R[ie * RSTRIDE + p * 16]     = p0;
        *(bf16x8*)&R[ie * RSTRIDE + p * 16 + 8] = p1;
    }
    __syncthreads();                                           // B5

    // ---- GEMM1c: kc 16..19 (ea cols) ----
    #pragma unroll
    for (int kcl = 0; kcl < 4; ++kcl) {
        bf16x8 a  = *(const bf16x8*)&R[(m0 + l31) * RSTRIDE + kcl * 16 + khalf * 8];
        bf16x8 b0 = W1[((16 + kcl) * 4 + n0q * 2 + 0) * 64 + lane];
        bf16x8 b1 = W1[((16 + kcl) * 4 + n0q * 2 + 1) * 64 + lane];
        acc0 = __builtin_amdgcn_mfma_f32_32x32x16_bf16(a, b0, acc0, 0, 0, 0);
        acc1 = __builtin_amdgcn_mfma_f32_32x32x16_bf16(a, b1, acc1, 0, 0, 0);
    }
    __syncthreads();                                           // B6

    // ---- h1 epilogue -> R ----
    #pragma unroll
    for (int nt = 0; nt < 2; ++nt) {
        f32x16 A = nt ? acc1 : acc0;
        int n = n0q * 64 + nt * 32 + l31;
        float bb = eb1[n];
        #pragma unroll
        for (int r = 0; r < 16; ++r) {
            int row = (r & 3) + 8 * (r >> 2) + 4 * khalf;
            R[(m0 + row) * RSTRIDE + n] = f2bf(silu_f(A[r] + bb));
        }
    }
    __syncthreads();                                           // B7

    // ---- GEMM2: msg = silu(h1 @ eW2 + eb2), K=128 ----
    #pragma unroll
    for (int r = 0; r < 16; ++r) { acc0[r] = 0.f; acc1[r] = 0.f; }
    #pragma unroll
    for (int kc = 0; kc < 8; ++kc) {
        bf16x8 a  = *(const bf16x8*)&R[(m0 + l31) * RSTRIDE + kc * 16 + khalf * 8];
        bf16x8 b0 = W2[(kc * 4 + n0q * 2 + 0) * 64 + lane];
        bf16x8 b1 = W2[(kc * 4 + n0q * 2 + 1) * 64 + lane];
        acc0 = __builtin_amdgcn_mfma_f32_32x32x16_bf16(a, b0, acc0, 0, 0, 0);
        acc1 = __builtin_amdgcn_mfma_f32_32x32x16_bf16(a, b1, acc1, 0, 0, 0);
    }
    __syncthreads();                                           // B8 (h1 dead)

    // ---- msg epilogue -> R ----
    #pragma unroll
    for (int nt = 0; nt < 2; ++nt) {
        f32x16 A = nt ? acc1 : acc0;
        int n = n0q * 64 + nt * 32 + l31;
        float bb = eb2[n];
        #pragma unroll
        for (int r = 0; r < 16; ++r) {
            int row = (r & 3) + 8 * (r >> 2) + 4 * khalf;
            R[(m0 + row) * RSTRIDE + n] = f2bf(silu_f(A[r] + bb));
        }
    }
    __syncthreads();                                           // B9

    // ---- GEMM3: h3 = silu(msg @ cW1 + cb1); per-edge w = h3 @ cW2 + cb2 ----
    {
        f32x16 c0, c1;
        #pragma unroll
        for (int r = 0; r < 16; ++r) { c0[r] = 0.f; c1[r] = 0.f; }
        #pragma unroll
        for (int kc = 0; kc < 8; ++kc) {
            bf16x8 a  = *(const bf16x8*)&R[(m0 + l31) * RSTRIDE + kc * 16 + khalf * 8];
            bf16x8 b0 = W3[(kc * 2 + 0) * 64 + lane];
            bf16x8 b1 = W3[(kc * 2 + 1) * 64 + lane];
            c0 = __builtin_amdgcn_mfma_f32_32x32x16_bf16(a, b0, c0, 0, 0, 0);
            c1 = __builtin_amdgcn_mfma_f32_32x32x16_bf16(a, b1, c1, 0, 0, 0);
        }
        float b1a = cb1[l31], b1b = cb1[32 + l31];
        float w2a = cW2[l31], w2b = cW2[32 + l31];
        float part[16];
        #pragma unroll
        for (int r = 0; r < 16; ++r)
            part[r] = silu_f(c0[r] + b1a) * w2a + silu_f(c1[r] + b1b) * w2b;
        #pragma unroll
        for (int r = 0; r < 16; ++r) {
            part[r] = SWZ_ADD(part[r], 0x041F);
            part[r] = SWZ_ADD(part[r], 0x081F);
            part[r] = SWZ_ADD(part[r], 0x101F);
            part[r] = SWZ_ADD(part[r], 0x201F);
            part[r] = SWZ_ADD(part[r], 0x401F);
        }
        if (l31 == 0) {
            float cb2v = cb2[0];
            #pragma unroll
            for (int r = 0; r < 16; ++r)
                s_wgt[m0 + (r & 3) + 8 * (r >> 2) + 4 * khalf] = part[r] + cb2v;
        }
    }
    __syncthreads();                                           // B10

    // ---- per-edge coord vector into LDS ----
    if (tid < MT) {
        int e = tid;
        float wgt = s_wgt[e];
        int s = s_src[e], d = s_dst[e];
        float dx = coords[s * 3 + 0] - coords[d * 3 + 0];
        float dy = coords[s * 3 + 1] - coords[d * 3 + 1];
        float dz = coords[s * 3 + 2] - coords[d * 3 + 2];
        float inv = wgt / (sqrtf(dx * dx + dy * dy + dz * dz) + EPS);
        s_cv[e][0] = dx * inv; s_cv[e][1] = dy * inv; s_cv[e][2] = dz * inv;
    }
    __syncthreads();                                           // B11

    // ---- message segment-reduction: thread = (column quad, row stripe) ----
    {
        int q  = tid & 31;        // cols q*4 .. q*4+3
        int st = tid >> 5;        // rows st*8 .. st*8+7
        int c0 = q * 4;
        float a0 = 0.f, a1 = 0.f, a2 = 0.f, a3 = 0.f;
        #pragma unroll
        for (int r = 0; r < 8; ++r) {
            int e = st * 8 + r;
            bf16x4 m = *(const bf16x4*)&R[e * RSTRIDE + c0];
            a0 += bf2f(m[0]); a1 += bf2f(m[1]); a2 += bf2f(m[2]); a3 += bf2f(m[3]);
            if (s_segend[e]) {
                float* ap = &aggr_nodes[(size_t)s_dst[e] * D + c0];
                unsafeAtomicAdd(ap + 0, a0); unsafeAtomicAdd(ap + 1, a1);
                unsafeAtomicAdd(ap + 2, a2); unsafeAtomicAdd(ap + 3, a3);
                a0 = a1 = a2 = a3 = 0.f;
            }
        }
        int elast = st * 8 + 7;
        if (!s_segend[elast]) {
            float* ap = &aggr_nodes[(size_t)s_dst[elast] * D + c0];
            unsafeAtomicAdd(ap + 0, a0); unsafeAtomicAdd(ap + 1, a1);
            unsafeAtomicAdd(ap + 2, a2); unsafeAtomicAdd(ap + 3, a3);
        }
    }

    // ---- coord segment-reduction: segment heads walk their run ----
    if (tid < MT) {
        int e = tid;
        bool head = (e == 0) || (s_dst[e] != s_dst[e - 1]);
        if (head) {
            float sx = 0.f, sy = 0.f, sz = 0.f;
            int j = e;
            do {
                sx += s_cv[j][0]; sy += s_cv[j][1]; sz += s_cv[j][2];
                ++j;
            } while (j < MT && s_dst[j] == s_dst[e]);
            int d = s_dst[e];
            unsafeAtomicAdd(&out_coords[d * 3 + 0], sx);
            unsafeAtomicAdd(&out_coords[d * 3 + 1], sy);
            unsafeAtomicAdd(&out_coords[d * 3 + 2], sz);
        }
    }
}

// ---------------------------------------------------------------------------
// node kernel (MFMA): 64 nodes/block; in-place aggr -> output.
// ---------------------------------------------------------------------------
__global__ __launch_bounds__(256, 4)
void node_kernel(const float* __restrict__ node_feat,
                 const short* __restrict__ nfbf,
                 float* nodes_io,
                 const float* __restrict__ nb1, const float* __restrict__ nb2,
                 const short* __restrict__ wsf) {
    __shared__ __align__(16) short lds[MT * NSTRIDE];
    const int tid = threadIdx.x;
    const int N0 = blockIdx.x * MT;

    {
        int i = tid >> 2, p = tid & 3;
        int nid = N0 + i; if (nid > N_NODES - 1) nid = N_NODES - 1;
        const short* frow = nfbf + (size_t)nid * D;
        short* drow = &lds[i * NSTRIDE];
        #pragma unroll
        for (int c = 0; c < 4; ++c)
            *(bf16x8*)&drow[c * 32 + p * 8] = *(const bf16x8*)&frow[c * 32 + p * 8];
        const float* arow = nodes_io + (size_t)nid * D + p * 32;
        #pragma unroll
        for (int c = 0; c < 4; ++c) {
            float4 f0 = *(const float4*)&arow[c * 8];
            float4 f1 = *(const float4*)&arow[c * 8 + 4];
            bf16x8 pk;
            pk[0]=f2bf(f0.x); pk[1]=f2bf(f0.y); pk[2]=f2bf(f0.z); pk[3]=f2bf(f0.w);
            pk[4]=f2bf(f1.x); pk[5]=f2bf(f1.y); pk[6]=f2bf(f1.z); pk[7]=f2bf(f1.w);
            *(bf16x8*)&drow[128 + p * 32 + c * 8] = pk;
        }
    }
    __syncthreads();

    const int lane  = tid & 63;
    const int wv    = tid >> 6;
    const int m0    = (wv >> 1) * 32;
    const int n0q   = wv & 1;
    const int l31   = lane & 31;
    const int khalf = lane >> 5;

    const bf16x8* W1 = (const bf16x8*)(wsf + NW1_OFF);
    const bf16x8* W2 = (const bf16x8*)(wsf + NW2_OFF);

    {
        f32x16 acc0, acc1;
        #pragma unroll
        for (int r = 0; r < 16; ++r) { acc0[r] = 0.f; acc1[r] = 0.f; }
        #pragma unroll
        for (int kc = 0; kc < 16; ++kc) {
            bf16x8 a  = *(const bf16x8*)&lds[(m0 + l31) * NSTRIDE + kc * 16 + khalf * 8];
            bf16x8 b0 = W1[(kc * 4 + n0q * 2 + 0) * 64 + lane];
            bf16x8 b1 = W1[(kc * 4 + n0q * 2 + 1) * 64 + lane];
            acc0 = __builtin_amdgcn_mfma_f32_32x32x16_bf16(a, b0, acc0, 0, 0, 0);
            acc1 = __builtin_amdgcn_mfma_f32_32x32x16_bf16(a, b1, acc1, 0, 0, 0);
        }
        __syncthreads();
        #pragma unroll
        for (int nt = 0; nt < 2; ++nt) {
            f32x16 A = nt ? acc1 : acc0;
            int n = n0q * 64 + nt * 32 + l31;
            float bb = nb1[n];
            #pragma unroll
            for (int r = 0; r < 16; ++r) {
                int row = (r & 3) + 8 * (r >> 2) + 4 * khalf;
                lds[(m0 + row) * HSTRIDE + n] = f2bf(silu_f(A[r] + bb));
            }
        }
    }
    __syncthreads();

    {
        f32x16 acc0, acc1;
        #pragma unroll
        for (int r = 0; r < 16; ++r) { acc0[r] = 0.f; acc1[r] = 0.f; }
        #pragma unroll
        for (int kc = 0; kc < 8; ++kc) {
            bf16x8 a  = *(const bf16x8*)&lds[(m0 + l31) * HSTRIDE + kc * 16 + khalf * 8];
            bf16x8 b0 = W2[(kc * 4 + n0q * 2 + 0) * 64 + lane];
            bf16x8 b1 = W2[(kc * 4 + n0q * 2 + 1) * 64 + lane];
            acc0 = __builtin_amdgcn_mfma_f32_32x32x16_bf16(a, b0, acc0, 0, 0, 0);
            acc1 = __builtin_amdgcn_mfma_f32_32x32x16_bf16(a, b1, acc1, 0, 0, 0);
        }
        #pragma unroll
        for (int nt = 0; nt < 2; ++nt) {
            f32x16 A = nt ? acc1 : acc0;
            int n = n0q * 64 + nt * 32 + l31;
            float bb = nb2[n];
            #pragma unroll
            for (int r = 0; r < 16; ++r) {
                int row = (r & 3) + 8 * (r >> 2) + 4 * khalf;
                int nid = N0 + m0 + row;
                if (nid < N_NODES)
                    nodes_io[(size_t)nid * D + n] = A[r] + bb + node_feat[(size_t)nid * D + n];
            }
        }
    }
}

extern "C" void kernel_launch(void* const* d_in, const int* in_sizes, int n_in,
                              void* d_out, int out_size, void* d_ws, size_t ws_size,
                              hipStream_t stream) {
    const float* node_feat  = (const float*)d_in[0];
    const int*   edge_index = (const int*)d_in[1];
    const float* edge_attr  = (const float*)d_in[2];
    const float* coords     = (const float*)d_in[3];
    const float* eW1 = (const float*)d_in[4];
    const float* eb1 = (const float*)d_in[5];
    const float* eW2 = (const float*)d_in[6];
    const float* eb2 = (const float*)d_in[7];
    const float* nW1 = (const float*)d_in[8];
    const float* nb1 = (const float*)d_in[9];
    const float* nW2 = (const float*)d_in[10];
    const float* nb2 = (const float*)d_in[11];
    const float* cW1 = (const float*)d_in[12];
    const float* cb1 = (const float*)d_in[13];
    const float* cW2 = (const float*)d_in[14];
    const float* cb2 = (const float*)d_in[15];

    float* nodes_io   = (float*)d_out;                 // aggr, then node output
    float* out_coords = nodes_io + (size_t)N_NODES * D;
    short* wsf    = (short*)d_ws;
    short* nfbf   = wsf + NFBF_OFF;
    int*   cnt    = (int*)(wsf + CSR_OFF);
    int*   cursor = cnt + N_NODES;
    int*   perm   = cursor + N_NODES;

    prep_kernel<<<256, 256, 0, stream>>>(
        eW1, eW2, cW1, nW1, nW2, node_feat, coords,
        wsf, nfbf, cnt, nodes_io, out_coords);
    hist_kernel<<<N_EDGES / 256, 256, 0, stream>>>(edge_index, cnt);
    scan_kernel<<<1, SCAN_T, 0, stream>>>(cnt, cursor);
    scatter_kernel<<<N_EDGES / 256, 256, 0, stream>>>(edge_index, cursor, perm);
    edge_kernel<<<N_EDGES / MT, 256, 0, stream>>>(
        nfbf, edge_index, perm, edge_attr, coords,
        eb1, eb2, cb1, cW2, cb2, wsf, nodes_io, out_coords);
    node_kernel<<<(N_NODES + MT - 1) / MT, 256, 0, stream>>>(
        node_feat, nfbf, nodes_io, nb1, nb2, wsf);
}

// Round 9
// 597.563 us; speedup vs baseline: 3.9356x; 1.0195x over previous
//
#include <hip/hip_runtime.h>
#include <math.h>

#define N_NODES 20000
#define N_EDGES 640000
#define D 128      // NODE_DIM == HID
#define ED 64      // EDGE_DIM
#define EPS 1e-8f
#define MT 64      // rows (edges/nodes) per block

#define RSTRIDE 136              // shared region row stride (bf16): 128 + 8 pad
#define HSTRIDE 136              // node kernel h1 stride
#define NSTRIDE 264              // node featA row stride: 256 + 8 pad

// d_ws layout (shorts unless noted):
//   eW1f @ 0 (80 frags) | eW2f @ 40960 | cW1f @ 57344 | nW1f @ 65536
//   nW2f @ 98304 | nfbf @ 114688 (2.56M shorts)
//   then i32: cnt @ short-ofs 2674688 (20000), cursor (+20000), perm (640000)
//   total 8,069,376 B  (ws_size proven >= 10.24 MB)
#define EW2_OFF 40960
#define CW1_OFF 57344
#define NW1_OFF 65536
#define NW2_OFF 98304
#define NFBF_OFF 114688
#define CSR_OFF  2674688   // in shorts; 4-byte aligned

typedef __attribute__((ext_vector_type(8))) short bf16x8;
typedef __attribute__((ext_vector_type(4))) short bf16x4;
typedef __attribute__((ext_vector_type(16))) float f32x16;

// fast silu: v_rcp + v_mul instead of IEEE-div expansion (~10 instr saved).
// rcp is ~1ulp; irrelevant vs bf16 threshold (measured absmax margin 4.7x).
__device__ __forceinline__ float silu_f(float x) {
    return __fdividef(x, 1.0f + __expf(-x));
}

__device__ __forceinline__ short f2bf(float f) {   // RNE f32 -> bf16
    union { float f; unsigned u; } v; v.f = f;
    unsigned r = v.u + 0x7FFFu + ((v.u >> 16) & 1u);
    return (short)(r >> 16);
}
__device__ __forceinline__ float bf2f(short s) {
    union { unsigned u; float f; } v;
    v.u = ((unsigned)(unsigned short)s) << 16;
    return v.f;
}

#define SWZ_ADD(x, imm) (x + __int_as_float( \
    __builtin_amdgcn_ds_swizzle(__float_as_int(x), imm)))

// ---------------------------------------------------------------------------
// prep: weights -> 32x32x16 B-frag order; node_feat -> bf16; zero aggr; zero
// CSR counters; seed out_coords = coords.
// ---------------------------------------------------------------------------
__global__ __launch_bounds__(256)
void prep_kernel(const float* __restrict__ eW1, const float* __restrict__ eW2,
                 const float* __restrict__ cW1, const float* __restrict__ nW1,
                 const float* __restrict__ nW2,
                 const float* __restrict__ node_feat,
                 const float* __restrict__ coords,
                 short* __restrict__ wsf, short* __restrict__ nfbf,
                 int* __restrict__ cnt,
                 float* __restrict__ nodes_io, float* __restrict__ out_coords) {
    const int t = blockIdx.x * blockDim.x + threadIdx.x;
    const int nthr = gridDim.x * blockDim.x;

    if (t < 224 * 64) {
        int f = t >> 6, lane = t & 63;
        const float* src; int kc, nt, ncol; size_t dst;
        if (f < 80)       {              src = eW1; kc = f >> 2;  nt = f & 3;  ncol = 128; dst = (size_t)f * 512; }
        else if (f < 112) { int g=f-80;  src = eW2; kc = g >> 2;  nt = g & 3;  ncol = 128; dst = EW2_OFF + (size_t)g * 512; }
        else if (f < 128) { int g=f-112; src = cW1; kc = g >> 1;  nt = g & 1;  ncol = 64;  dst = CW1_OFF + (size_t)g * 512; }
        else if (f < 192) { int g=f-128; src = nW1; kc = g >> 2;  nt = g & 3;  ncol = 128; dst = NW1_OFF + (size_t)g * 512; }
        else              { int g=f-192; src = nW2; kc = g >> 2;  nt = g & 3;  ncol = 128; dst = NW2_OFF + (size_t)g * 512; }
        int col = nt * 32 + (lane & 31);
        int k0  = kc * 16 + (lane >> 5) * 8;
        bf16x8 o;
        #pragma unroll
        for (int j = 0; j < 8; ++j) o[j] = f2bf(src[(size_t)(k0 + j) * ncol + col]);
        *(bf16x8*)&wsf[dst + (size_t)lane * 8] = o;
    }
    for (int idx = t; idx < N_NODES * D / 8; idx += nthr) {
        const float* s = node_feat + (size_t)idx * 8;
        float4 f0 = *(const float4*)s, f1 = *(const float4*)(s + 4);
        bf16x8 pk;
        pk[0]=f2bf(f0.x); pk[1]=f2bf(f0.y); pk[2]=f2bf(f0.z); pk[3]=f2bf(f0.w);
        pk[4]=f2bf(f1.x); pk[5]=f2bf(f1.y); pk[6]=f2bf(f1.z); pk[7]=f2bf(f1.w);
        *(bf16x8*)&nfbf[(size_t)idx * 8] = pk;
    }
    for (int idx = t; idx < N_NODES * D / 4; idx += nthr) {
        float4 z; z.x = 0.f; z.y = 0.f; z.z = 0.f; z.w = 0.f;
        *(float4*)&nodes_io[(size_t)idx * 4] = z;
    }
    for (int idx = t; idx < N_NODES; idx += nthr) cnt[idx] = 0;
    for (int idx = t; idx < N_NODES * 3; idx += nthr)
        out_coords[idx] = coords[idx];
}

// ---------------------------------------------------------------------------
// CSR build: histogram -> exclusive scan (LDS-staged, coalesced) -> scatter.
// ---------------------------------------------------------------------------
__global__ __launch_bounds__(256)
void hist_kernel(const int* __restrict__ edge_index, int* __restrict__ cnt) {
    int t = blockIdx.x * blockDim.x + threadIdx.x;
    if (t < N_EDGES) atomicAdd(&cnt[edge_index[N_EDGES + t]], 1);
}

#define SCAN_T 1024
#define SCAN_C 20
__global__ __launch_bounds__(SCAN_T)
void scan_kernel(const int* __restrict__ cnt, int* __restrict__ cursor) {
    __shared__ int lc[N_NODES];      // 80 KB, single block
    __shared__ int part[SCAN_T];
    const int t = threadIdx.x;
    for (int i = t * 4; i < N_NODES; i += SCAN_T * 4)
        *(int4*)&lc[i] = *(const int4*)&cnt[i];
    __syncthreads();
    const int base = t * SCAN_C;
    int s = 0;
    #pragma unroll
    for (int i = 0; i < SCAN_C; ++i) {
        int idx = base + i;
        if (idx < N_NODES) s += lc[idx];
    }
    part[t] = s;
    __syncthreads();
    for (int off = 1; off < SCAN_T; off <<= 1) {
        int v = (t >= off) ? part[t - off] : 0;
        __syncthreads();
        part[t] += v;
        __syncthreads();
    }
    int run = part[t] - s;   // exclusive prefix of this thread's chunk
    #pragma unroll
    for (int i = 0; i < SCAN_C; ++i) {
        int idx = base + i;
        if (idx < N_NODES) { int c = lc[idx]; lc[idx] = run; run += c; }
    }
    __syncthreads();
    for (int i = t * 4; i < N_NODES; i += SCAN_T * 4)
        *(int4*)&cursor[i] = *(const int4*)&lc[i];
}

__global__ __launch_bounds__(256)
void scatter_kernel(const int* __restrict__ edge_index,
                    int* __restrict__ cursor, int* __restrict__ perm) {
    int t = blockIdx.x * blockDim.x + threadIdx.x;
    if (t < N_EDGES) {
        int d = edge_index[N_EDGES + t];
        int pos = atomicAdd(&cursor[d], 1);
        perm[pos] = t;
    }
}

// ---------------------------------------------------------------------------
// edge kernel: 64 dst-sorted edges/block. 3-chunk staged GEMM1 through one
// 17.4 KB region reused for h1/msg. GEMM3 split across wave pairs by column
// half (no duplicated work); partials merged via LDS float atomics.
// ---------------------------------------------------------------------------
__global__ __launch_bounds__(256, 6)
void edge_kernel(const short* __restrict__ nfbf,
                 const int* __restrict__ edge_index,
                 const int* __restrict__ perm,
                 const float* __restrict__ edge_attr,
                 const float* __restrict__ coords,
                 const float* __restrict__ eb1, const float* __restrict__ eb2,
                 const float* __restrict__ cb1, const float* __restrict__ cW2,
                 const float* __restrict__ cb2,
                 const short* __restrict__ wsf,
                 float* __restrict__ aggr_nodes, float* __restrict__ out_coords) {
    __shared__ __align__(16) short R[MT * RSTRIDE];   // 8704 shorts = 17408 B
    __shared__ int s_src[MT], s_dst[MT];
    __shared__ float s_wgt[MT];
    __shared__ float s_cv[MT][3];
    __shared__ char s_segend[MT];

    const int tid = threadIdx.x;
    const int E0 = blockIdx.x * MT;

    const int ie = tid >> 2, p = tid & 3;       // 4 threads/edge
    const int eid  = perm[E0 + ie];
    const int esrc = edge_index[eid];
    const int edst = edge_index[N_EDGES + eid];
    if (p == 0) { s_src[ie] = esrc; s_dst[ie] = edst; }
    if (tid < MT) s_wgt[tid] = 0.0f;

    // ---- stage chunk 0: src rows ----
    {
        const short* row = nfbf + (size_t)esrc * D;
        #pragma unroll
        for (int c = 0; c < 4; ++c)
            *(bf16x8*)&R[ie * RSTRIDE + c * 32 + p * 8] = *(const bf16x8*)&row[c * 32 + p * 8];
    }
    __syncthreads();                                           // B1
    if (tid < MT)
        s_segend[tid] = (tid == MT - 1) || (s_dst[tid] != s_dst[tid + 1]);

    const int lane  = tid & 63;
    const int wv    = tid >> 6;
    const int m0    = (wv >> 1) * 32;
    const int n0q   = wv & 1;
    const int l31   = lane & 31;
    const int khalf = lane >> 5;

    const bf16x8* W1 = (const bf16x8*)wsf;
    const bf16x8* W2 = (const bf16x8*)(wsf + EW2_OFF);
    const bf16x8* W3 = (const bf16x8*)(wsf + CW1_OFF);

    f32x16 acc0, acc1;
    #pragma unroll
    for (int r = 0; r < 16; ++r) { acc0[r] = 0.f; acc1[r] = 0.f; }

    // ---- GEMM1a: kc 0..7 (src cols) ----
    #pragma unroll
    for (int kcl = 0; kcl < 8; ++kcl) {
        bf16x8 a  = *(const bf16x8*)&R[(m0 + l31) * RSTRIDE + kcl * 16 + khalf * 8];
        bf16x8 b0 = W1[((kcl) * 4 + n0q * 2 + 0) * 64 + lane];
        bf16x8 b1 = W1[((kcl) * 4 + n0q * 2 + 1) * 64 + lane];
        acc0 = __builtin_amdgcn_mfma_f32_32x32x16_bf16(a, b0, acc0, 0, 0, 0);
        acc1 = __builtin_amdgcn_mfma_f32_32x32x16_bf16(a, b1, acc1, 0, 0, 0);
    }
    __syncthreads();                                           // B2

    // ---- stage chunk 1: dst rows ----
    {
        const short* row = nfbf + (size_t)edst * D;
        #pragma unroll
        for (int c = 0; c < 4; ++c)
            *(bf16x8*)&R[ie * RSTRIDE + c * 32 + p * 8] = *(const bf16x8*)&row[c * 32 + p * 8];
    }
    __syncthreads();                                           // B3

    // ---- GEMM1b: kc 8..15 (dst cols) ----
    #pragma unroll
    for (int kcl = 0; kcl < 8; ++kcl) {
        bf16x8 a  = *(const bf16x8*)&R[(m0 + l31) * RSTRIDE + kcl * 16 + khalf * 8];
        bf16x8 b0 = W1[((8 + kcl) * 4 + n0q * 2 + 0) * 64 + lane];
        bf16x8 b1 = W1[((8 + kcl) * 4 + n0q * 2 + 1) * 64 + lane];
        acc0 = __builtin_amdgcn_mfma_f32_32x32x16_bf16(a, b0, acc0, 0, 0, 0);
        acc1 = __builtin_amdgcn_mfma_f32_32x32x16_bf16(a, b1, acc1, 0, 0, 0);
    }
    __syncthreads();                                           // B4

    // ---- stage chunk 2: edge_attr (64 cols, f32->bf16) ----
    {
        const float* arow = edge_attr + (size_t)eid * ED + p * 16;
        float4 a0 = *(const float4*)&arow[0], a1 = *(const float4*)&arow[4];
        float4 a2 = *(const float4*)&arow[8], a3 = *(const float4*)&arow[12];
        bf16x8 p0, p1;
        p0[0]=f2bf(a0.x); p0[1]=f2bf(a0.y); p0[2]=f2bf(a0.z); p0[3]=f2bf(a0.w);
        p0[4]=f2bf(a1.x); p0[5]=f2bf(a1.y); p0[6]=f2bf(a1.z); p0[7]=f2bf(a1.w);
        p1[0]=f2bf(a2.x); p1[1]=f2bf(a2.y); p1[2]=f2bf(a2.z); p1[3]=f2bf(a2.w);
        p1[4]=f2bf(a3.x); p1[5]=f2bf(a3.y); p1[6]=f2bf(a3.z); p1[7]=f2bf(a3.w);
        *(bf16x8*)&R[ie * RSTRIDE + p * 16]     = p0;
        *(bf16x8*)&R[ie * RSTRIDE + p * 16 + 8] = p1;
    }
    __syncthreads();                                           // B5

    // ---- GEMM1c: kc 16..19 (ea cols) ----
    #pragma unroll
    for (int kcl = 0; kcl < 4; ++kcl) {
        bf16x8 a  = *(const bf16x8*)&R[(m0 + l31) * RSTRIDE + kcl * 16 + khalf * 8];
        bf16x8 b0 = W1[((16 + kcl) * 4 + n0q * 2 + 0) * 64 + lane];
        bf16x8 b1 = W1[((16 + kcl) * 4 + n0q * 2 + 1) * 64 + lane];
        acc0 = __builtin_amdgcn_mfma_f32_32x32x16_bf16(a, b0, acc0, 0, 0, 0);
        acc1 = __builtin_amdgcn_mfma_f32_32x32x16_bf16(a, b1, acc1, 0, 0, 0);
    }
    __syncthreads();                                           // B6

    // ---- h1 epilogue -> R ----
    #pragma unroll
    for (int nt = 0; nt < 2; ++nt) {
        f32x16 A = nt ? acc1 : acc0;
        int n = n0q * 64 + nt * 32 + l31;
        float bb = eb1[n];
        #pragma unroll
        for (int r = 0; r < 16; ++r) {
            int row = (r & 3) + 8 * (r >> 2) + 4 * khalf;
            R[(m0 + row) * RSTRIDE + n] = f2bf(silu_f(A[r] + bb));
        }
    }
    __syncthreads();                                           // B7

    // ---- GEMM2: msg = silu(h1 @ eW2 + eb2), K=128 ----
    #pragma unroll
    for (int r = 0; r < 16; ++r) { acc0[r] = 0.f; acc1[r] = 0.f; }
    #pragma unroll
    for (int kc = 0; kc < 8; ++kc) {
        bf16x8 a  = *(const bf16x8*)&R[(m0 + l31) * RSTRIDE + kc * 16 + khalf * 8];
        bf16x8 b0 = W2[(kc * 4 + n0q * 2 + 0) * 64 + lane];
        bf16x8 b1 = W2[(kc * 4 + n0q * 2 + 1) * 64 + lane];
        acc0 = __builtin_amdgcn_mfma_f32_32x32x16_bf16(a, b0, acc0, 0, 0, 0);
        acc1 = __builtin_amdgcn_mfma_f32_32x32x16_bf16(a, b1, acc1, 0, 0, 0);
    }
    __syncthreads();                                           // B8 (h1 dead)

    // ---- msg epilogue -> R ----
    #pragma unroll
    for (int nt = 0; nt < 2; ++nt) {
        f32x16 A = nt ? acc1 : acc0;
        int n = n0q * 64 + nt * 32 + l31;
        float bb = eb2[n];
        #pragma unroll
        for (int r = 0; r < 16; ++r) {
            int row = (r & 3) + 8 * (r >> 2) + 4 * khalf;
            R[(m0 + row) * RSTRIDE + n] = f2bf(silu_f(A[r] + bb));
        }
    }
    __syncthreads();                                           // B9

    // ---- GEMM3 (split): wave pair handles rows m0..m0+31; this wave takes
    // column half n0q (32 cols, 8 MFMA). Partials merged via ds_add. ----
    {
        f32x16 c0;
        #pragma unroll
        for (int r = 0; r < 16; ++r) c0[r] = 0.f;
        #pragma unroll
        for (int kc = 0; kc < 8; ++kc) {
            bf16x8 a = *(const bf16x8*)&R[(m0 + l31) * RSTRIDE + kc * 16 + khalf * 8];
            bf16x8 b = W3[(kc * 2 + n0q) * 64 + lane];
            c0 = __builtin_amdgcn_mfma_f32_32x32x16_bf16(a, b, c0, 0, 0, 0);
        }
        int ncol = n0q * 32 + l31;
        float b1a = cb1[ncol];
        float w2a = cW2[ncol];
        float part[16];
        #pragma unroll
        for (int r = 0; r < 16; ++r)
            part[r] = silu_f(c0[r] + b1a) * w2a;
        #pragma unroll
        for (int r = 0; r < 16; ++r) {
            part[r] = SWZ_ADD(part[r], 0x041F);
            part[r] = SWZ_ADD(part[r], 0x081F);
            part[r] = SWZ_ADD(part[r], 0x101F);
            part[r] = SWZ_ADD(part[r], 0x201F);
            part[r] = SWZ_ADD(part[r], 0x401F);
        }
        if (l31 == 0) {
            #pragma unroll
            for (int r = 0; r < 16; ++r)
                atomicAdd(&s_wgt[m0 + (r & 3) + 8 * (r >> 2) + 4 * khalf], part[r]);
        }
    }
    __syncthreads();                                           // B10

    // ---- per-edge coord vector into LDS ----
    if (tid < MT) {
        int e = tid;
        float wgt = s_wgt[e] + cb2[0];
        int s = s_src[e], d = s_dst[e];
        float dx = coords[s * 3 + 0] - coords[d * 3 + 0];
        float dy = coords[s * 3 + 1] - coords[d * 3 + 1];
        float dz = coords[s * 3 + 2] - coords[d * 3 + 2];
        float inv = __fdividef(wgt, sqrtf(dx * dx + dy * dy + dz * dz) + EPS);
        s_cv[e][0] = dx * inv; s_cv[e][1] = dy * inv; s_cv[e][2] = dz * inv;
    }
    __syncthreads();                                           // B11

    // ---- message segment-reduction: thread = (column quad, row stripe) ----
    {
        int q  = tid & 31;        // cols q*4 .. q*4+3
        int st = tid >> 5;        // rows st*8 .. st*8+7
        int c0 = q * 4;
        float a0 = 0.f, a1 = 0.f, a2 = 0.f, a3 = 0.f;
        #pragma unroll
        for (int r = 0; r < 8; ++r) {
            int e = st * 8 + r;
            bf16x4 m = *(const bf16x4*)&R[e * RSTRIDE + c0];
            a0 += bf2f(m[0]); a1 += bf2f(m[1]); a2 += bf2f(m[2]); a3 += bf2f(m[3]);
            if (s_segend[e]) {
                float* ap = &aggr_nodes[(size_t)s_dst[e] * D + c0];
                unsafeAtomicAdd(ap + 0, a0); unsafeAtomicAdd(ap + 1, a1);
                unsafeAtomicAdd(ap + 2, a2); unsafeAtomicAdd(ap + 3, a3);
                a0 = a1 = a2 = a3 = 0.f;
            }
        }
        int elast = st * 8 + 7;
        if (!s_segend[elast]) {
            float* ap = &aggr_nodes[(size_t)s_dst[elast] * D + c0];
            unsafeAtomicAdd(ap + 0, a0); unsafeAtomicAdd(ap + 1, a1);
            unsafeAtomicAdd(ap + 2, a2); unsafeAtomicAdd(ap + 3, a3);
        }
    }

    // ---- coord segment-reduction: segment heads walk their run ----
    if (tid < MT) {
        int e = tid;
        bool head = (e == 0) || (s_dst[e] != s_dst[e - 1]);
        if (head) {
            float sx = 0.f, sy = 0.f, sz = 0.f;
            int j = e;
            do {
                sx += s_cv[j][0]; sy += s_cv[j][1]; sz += s_cv[j][2];
                ++j;
            } while (j < MT && s_dst[j] == s_dst[e]);
            int d = s_dst[e];
            unsafeAtomicAdd(&out_coords[d * 3 + 0], sx);
            unsafeAtomicAdd(&out_coords[d * 3 + 1], sy);
            unsafeAtomicAdd(&out_coords[d * 3 + 2], sz);
        }
    }
}

// ---------------------------------------------------------------------------
// node kernel (MFMA): 64 nodes/block; in-place aggr -> output.
// ---------------------------------------------------------------------------
__global__ __launch_bounds__(256, 4)
void node_kernel(const float* __restrict__ node_feat,
                 const short* __restrict__ nfbf,
                 float* nodes_io,
                 const float* __restrict__ nb1, const float* __restrict__ nb2,
                 const short* __restrict__ wsf) {
    __shared__ __align__(16) short lds[MT * NSTRIDE];
    const int tid = threadIdx.x;
    const int N0 = blockIdx.x * MT;

    {
        int i = tid >> 2, p = tid & 3;
        int nid = N0 + i; if (nid > N_NODES - 1) nid = N_NODES - 1;
        const short* frow = nfbf + (size_t)nid * D;
        short* drow = &lds[i * NSTRIDE];
        #pragma unroll
        for (int c = 0; c < 4; ++c)
            *(bf16x8*)&drow[c * 32 + p * 8] = *(const bf16x8*)&frow[c * 32 + p * 8];
        const float* arow = nodes_io + (size_t)nid * D + p * 32;
        #pragma unroll
        for (int c = 0; c < 4; ++c) {
            float4 f0 = *(const float4*)&arow[c * 8];
            float4 f1 = *(const float4*)&arow[c * 8 + 4];
            bf16x8 pk;
            pk[0]=f2bf(f0.x); pk[1]=f2bf(f0.y); pk[2]=f2bf(f0.z); pk[3]=f2bf(f0.w);
            pk[4]=f2bf(f1.x); pk[5]=f2bf(f1.y); pk[6]=f2bf(f1.z); pk[7]=f2bf(f1.w);
            *(bf16x8*)&drow[128 + p * 32 + c * 8] = pk;
        }
    }
    __syncthreads();

    const int lane  = tid & 63;
    const int wv    = tid >> 6;
    const int m0    = (wv >> 1) * 32;
    const int n0q   = wv & 1;
    const int l31   = lane & 31;
    const int khalf = lane >> 5;

    const bf16x8* W1 = (const bf16x8*)(wsf + NW1_OFF);
    const bf16x8* W2 = (const bf16x8*)(wsf + NW2_OFF);

    {
        f32x16 acc0, acc1;
        #pragma unroll
        for (int r = 0; r < 16; ++r) { acc0[r] = 0.f; acc1[r] = 0.f; }
        #pragma unroll
        for (int kc = 0; kc < 16; ++kc) {
            bf16x8 a  = *(const bf16x8*)&lds[(m0 + l31) * NSTRIDE + kc * 16 + khalf * 8];
            bf16x8 b0 = W1[(kc * 4 + n0q * 2 + 0) * 64 + lane];
            bf16x8 b1 = W1[(kc * 4 + n0q * 2 + 1) * 64 + lane];
            acc0 = __builtin_amdgcn_mfma_f32_32x32x16_bf16(a, b0, acc0, 0, 0, 0);
            acc1 = __builtin_amdgcn_mfma_f32_32x32x16_bf16(a, b1, acc1, 0, 0, 0);
        }
        __syncthreads();
        #pragma unroll
        for (int nt = 0; nt < 2; ++nt) {
            f32x16 A = nt ? acc1 : acc0;
            int n = n0q * 64 + nt * 32 + l31;
            float bb = nb1[n];
            #pragma unroll
            for (int r = 0; r < 16; ++r) {
                int row = (r & 3) + 8 * (r >> 2) + 4 * khalf;
                lds[(m0 + row) * HSTRIDE + n] = f2bf(silu_f(A[r] + bb));
            }
        }
    }
    __syncthreads();

    {
        f32x16 acc0, acc1;
        #pragma unroll
        for (int r = 0; r < 16; ++r) { acc0[r] = 0.f; acc1[r] = 0.f; }
        #pragma unroll
        for (int kc = 0; kc < 8; ++kc) {
            bf16x8 a  = *(const bf16x8*)&lds[(m0 + l31) * HSTRIDE + kc * 16 + khalf * 8];
            bf16x8 b0 = W2[(kc * 4 + n0q * 2 + 0) * 64 + lane];
            bf16x8 b1 = W2[(kc * 4 + n0q * 2 + 1) * 64 + lane];
            acc0 = __builtin_amdgcn_mfma_f32_32x32x16_bf16(a, b0, acc0, 0, 0, 0);
            acc1 = __builtin_amdgcn_mfma_f32_32x32x16_bf16(a, b1, acc1, 0, 0, 0);
        }
        #pragma unroll
        for (int nt = 0; nt < 2; ++nt) {
            f32x16 A = nt ? acc1 : acc0;
            int n = n0q * 64 + nt * 32 + l31;
            float bb = nb2[n];
            #pragma unroll
            for (int r = 0; r < 16; ++r) {
                int row = (r & 3) + 8 * (r >> 2) + 4 * khalf;
                int nid = N0 + m0 + row;
                if (nid < N_NODES)
                    nodes_io[(size_t)nid * D + n] = A[r] + bb + node_feat[(size_t)nid * D + n];
            }
        }
    }
}

extern "C" void kernel_launch(void* const* d_in, const int* in_sizes, int n_in,
                              void* d_out, int out_size, void* d_ws, size_t ws_size,
                              hipStream_t stream) {
    const float* node_feat  = (const float*)d_in[0];
    const int*   edge_index = (const int*)d_in[1];
    const float* edge_attr  = (const float*)d_in[2];
    const float* coords     = (const float*)d_in[3];
    const float* eW1 = (const float*)d_in[4];
    const float* eb1 = (const float*)d_in[5];
    const float* eW2 = (const float*)d_in[6];
    const float* eb2 = (const float*)d_in[7];
    const float* nW1 = (const float*)d_in[8];
    const float* nb1 = (const float*)d_in[9];
    const float* nW2 = (const float*)d_in[10];
    const float* nb2 = (const float*)d_in[11];
    const float* cW1 = (const float*)d_in[12];
    const float* cb1 = (const float*)d_in[13];
    const float* cW2 = (const float*)d_in[14];
    const float* cb2 = (const float*)d_in[15];

    float* nodes_io   = (float*)d_out;                 // aggr, then node output
    float* out_coords = nodes_io + (size_t)N_NODES * D;
    short* wsf    = (short*)d_ws;
    short* nfbf   = wsf + NFBF_OFF;
    int*   cnt    = (int*)(wsf + CSR_OFF);
    int*   cursor = cnt + N_NODES;
    int*   perm   = cursor + N_NODES;

    prep_kernel<<<256, 256, 0, stream>>>(
        eW1, eW2, cW1, nW1, nW2, node_feat, coords,
        wsf, nfbf, cnt, nodes_io, out_coords);
    hist_kernel<<<N_EDGES / 256, 256, 0, stream>>>(edge_index, cnt);
    scan_kernel<<<1, SCAN_T, 0, stream>>>(cnt, cursor);
    scatter_kernel<<<N_EDGES / 256, 256, 0, stream>>>(edge_index, cursor, perm);
    edge_kernel<<<N_EDGES / MT, 256, 0, stream>>>(
        nfbf, edge_index, perm, edge_attr, coords,
        eb1, eb2, cb1, cW2, cb2, wsf, nodes_io, out_coords);
    node_kernel<<<(N_NODES + MT - 1) / MT, 256, 0, stream>>>(
        node_feat, nfbf, nodes_io, nb1, nb2, wsf);
}